// Round 3
// baseline (1134.048 us; speedup 1.0000x reference)
//
#include <hip/hip_runtime.h>
#include <stdint.h>
#include <stddef.h>

typedef __bf16 bf16;
typedef __attribute__((ext_vector_type(8))) __bf16 bf16x8;
typedef __attribute__((ext_vector_type(4))) float floatx4;

#define GAS __attribute__((address_space(1)))
#define LAS __attribute__((address_space(3)))

__device__ __forceinline__ void async16(const void* g, void* l) {
  __builtin_amdgcn_global_load_lds((const GAS void*)g, (LAS void*)l, 16, 0, 0);
}

__device__ __forceinline__ bf16x8 cvt8(const float* p) {
  floatx4 a = *(const floatx4*)p;
  floatx4 b = *(const floatx4*)(p + 4);
  bf16x8 r;
  r[0] = (bf16)a[0]; r[1] = (bf16)a[1]; r[2] = (bf16)a[2]; r[3] = (bf16)a[3];
  r[4] = (bf16)b[0]; r[5] = (bf16)b[1]; r[6] = (bf16)b[2]; r[7] = (bf16)b[3];
  return r;
}

// ---------------------------------------------------------------------------
// Generic "bt" GEMM: C[M,N] = A[M,K] @ B[N,K]^T, row-major K-contig operands.
// AF/BF: operand dtype is f32 (external input, VGPR load + cvt + ds_write
// staging) vs bf16 (internal, async global_load_lds staging).
// 128x128 tile, BK=32, 256 thr (4 waves, 2x2 of 64x64), mfma 16x16x32 bf16.
// EPI: 0 bf16 store | 1 f32 atomicAdd (split-K) | 2 f32 softplus(v+bias) |
//      3 f32 (v+bias)
// ---------------------------------------------------------------------------
template <int EPI, int AF, int BF>
__global__ __launch_bounds__(256, 2) void gemm_bt(
    const void* __restrict__ Aptr, const void* __restrict__ Bptr,
    void* __restrict__ Cout, const float* __restrict__ bias,
    int M, int N, int K) {
  __shared__ bf16 As[128 * 32];
  __shared__ bf16 Bs[128 * 32];
  const int tid = threadIdx.x;

  const int rowBase = blockIdx.x * 128;
  const int colBase = blockIdx.y * 128;
  const int kLen = K / gridDim.z;
  const int k0 = blockIdx.z * kLen;
  const int kIters = kLen / 32;

  // staging map: chunk c = tid (+256); row = c/4, kcol = (c%4)*8;
  // LDS offset = c*16B (linear in tid) -> satisfies global_load_lds's
  // wave-uniform-base + lane*16 requirement.
  const int sRow = tid >> 2;
  const int sCol = (tid & 3) << 3;
  const int wave = tid >> 6;
  const int lane = tid & 63;
  const int wm = (wave >> 1) << 6;  // 0 / 64
  const int wn = (wave & 1) << 6;   // 0 / 64
  const int lr = lane & 15;
  const int kg = lane >> 4;

  floatx4 acc[4][4] = {};

  for (int kt = 0; kt < kIters; ++kt) {
    const int kk = k0 + kt * 32;
    __syncthreads();  // prev iter's LDS reads done before overwrite
    if constexpr (AF) {
      const float* pa = (const float*)Aptr + (size_t)(rowBase + sRow) * K + kk + sCol;
      *(bf16x8*)&As[tid * 8] = cvt8(pa);
      *(bf16x8*)&As[2048 + tid * 8] = cvt8(pa + (size_t)64 * K);
    } else {
      const bf16* pa = (const bf16*)Aptr + (size_t)(rowBase + sRow) * K + kk + sCol;
      async16(pa, &As[tid * 8]);
      async16(pa + (size_t)64 * K, &As[2048 + tid * 8]);
    }
    if constexpr (BF) {
      const float* pb = (const float*)Bptr + (size_t)(colBase + sRow) * K + kk + sCol;
      *(bf16x8*)&Bs[tid * 8] = cvt8(pb);
      *(bf16x8*)&Bs[2048 + tid * 8] = cvt8(pb + (size_t)64 * K);
    } else {
      const bf16* pb = (const bf16*)Bptr + (size_t)(colBase + sRow) * K + kk + sCol;
      async16(pb, &Bs[tid * 8]);
      async16(pb + (size_t)64 * K, &Bs[2048 + tid * 8]);
    }
    __syncthreads();  // staging complete -> tile visible

    bf16x8 af[4], bg[4];
#pragma unroll
    for (int i = 0; i < 4; ++i)
      af[i] = *(const bf16x8*)&As[(wm + i * 16 + lr) * 32 + kg * 8];
#pragma unroll
    for (int j = 0; j < 4; ++j)
      bg[j] = *(const bf16x8*)&Bs[(wn + j * 16 + lr) * 32 + kg * 8];
#pragma unroll
    for (int i = 0; i < 4; ++i)
#pragma unroll
      for (int j = 0; j < 4; ++j)
        acc[i][j] = __builtin_amdgcn_mfma_f32_16x16x32_bf16(af[i], bg[j],
                                                            acc[i][j], 0, 0, 0);
  }

  // epilogue: C/D layout col = lane&15, row = (lane>>4)*4 + reg  [m89]
#pragma unroll
  for (int i = 0; i < 4; ++i) {
#pragma unroll
    for (int j = 0; j < 4; ++j) {
      const int col = colBase + wn + j * 16 + lr;
      float bv = 0.f;
      if constexpr (EPI == 2 || EPI == 3) bv = bias[col];
#pragma unroll
      for (int r = 0; r < 4; ++r) {
        const int row = rowBase + wm + i * 16 + kg * 4 + r;
        const size_t idx = (size_t)row * N + col;
        float v = acc[i][j][r];
        if constexpr (EPI == 0) {
          ((bf16*)Cout)[idx] = (bf16)v;
        } else if constexpr (EPI == 1) {
          atomicAdd((float*)Cout + idx, v);
        } else if constexpr (EPI == 2) {
          v += bv;  // softplus = max(v,0) + log1p(exp(-|v|))
          v = fmaxf(v, 0.f) + log1pf(__expf(-fabsf(v)));
          ((float*)Cout)[idx] = v;
        } else {
          ((float*)Cout)[idx] = v + bv;
        }
      }
    }
  }
}

// W_x (160x4096 f32) -> WXPAD (256x4096 bf16), zero rows >= 160.
__global__ void wxpad_prep(const float* __restrict__ Wx,
                           bf16* __restrict__ WXPAD) {
  const int idx = blockIdx.x * 256 + threadIdx.x;  // 256*4096
  const int row = idx >> 12;
  WXPAD[idx] = (row < 160) ? (bf16)Wx[idx] : (bf16)0.f;
}

// Depthwise causal conv (K=4) + bias + SiLU over XZ's x half.
__global__ void conv_kernel(const bf16* __restrict__ XZ,
                            const float* __restrict__ conv_w,
                            const float* __restrict__ conv_b,
                            bf16* __restrict__ XC) {
  const int idx = blockIdx.x * 256 + threadIdx.x;  // 2048*4096
  const int d = idx & 4095;
  const int row = idx >> 12;
  const int l = row & 1023;
  float acc = conv_b[d];
#pragma unroll
  for (int k = 0; k < 4; ++k) {
    if (l - 3 + k >= 0)
      acc += conv_w[d * 4 + k] * (float)XZ[(size_t)(row - 3 + k) * 8192 + d];
  }
  const float s = acc / (1.f + __expf(-acc));
  XC[(size_t)row * 4096 + d] = (bf16)s;
}

// conv_state output (f32): out[b,d,k] = x[b, 1020+k, d]
__global__ void convstate_kernel(const bf16* __restrict__ XZ,
                                 float* __restrict__ outConv) {
  const int idx = blockIdx.x * 256 + threadIdx.x;  // 32768
  const int k = idx & 3;
  const int d = (idx >> 2) & 4095;
  const int b = idx >> 14;
  outConv[idx] = (float)XZ[(size_t)(b * 1024 + 1020 + k) * 8192 + d];
}

// dt columns of XDBL (f32 2048x256) -> DT bf16 (2048x128)
__global__ void dtcast_kernel(const float* __restrict__ XDBL,
                              bf16* __restrict__ DT) {
  const int idx = blockIdx.x * 256 + threadIdx.x;  // 2048*128
  const int row = idx >> 7;
  const int r = idx & 127;
  DT[idx] = (bf16)XDBL[row * 256 + r];
}

// ---------------------------------------------------------------------------
// Selective scan, one thread per (b,d), 16 states in regs, software-pipelined.
// Fuses (y + D*u)*silu(z); writes Y bf16 (internal) and last_state f32 (out).
// ---------------------------------------------------------------------------
__global__ __launch_bounds__(64) void scan_kernel(
    const float* __restrict__ DELTA, const bf16* __restrict__ XC,
    const bf16* __restrict__ XZ, const float* __restrict__ XDBL,
    const float* __restrict__ A_log, const float* __restrict__ Dp,
    bf16* __restrict__ Y, float* __restrict__ lastOut) {
  const int g = blockIdx.x * 64 + threadIdx.x;  // 0..8191
  const int b = g >> 12;
  const int d = g & 4095;
  const float LOG2E = 1.44269504088896f;
  float A2[16], st[16];
#pragma unroll
  for (int n = 0; n < 16; ++n) {
    A2[n] = -__expf(A_log[d * 16 + n]) * LOG2E;  // A * log2(e)
    st[n] = 0.f;
  }
  const float Dd = Dp[d];
  size_t row = (size_t)b << 10;

  float dlt = DELTA[row * 4096 + d];
  float u = (float)XC[row * 4096 + d];
  float z = (float)XZ[row * 8192 + 4096 + d];
  floatx4 Bv[4], Cv[4];
  {
    const float* Bp = XDBL + row * 256 + 128;
#pragma unroll
    for (int q = 0; q < 4; ++q) {
      Bv[q] = *(const floatx4*)(Bp + q * 4);
      Cv[q] = *(const floatx4*)(Bp + 16 + q * 4);
    }
  }
  for (int l = 0; l < 1024; ++l) {
    float dlt_n = 0.f, u_n = 0.f, z_n = 0.f;
    floatx4 Bn[4], Cn[4];
    if (l < 1023) {
      const size_t r2 = row + 1;
      dlt_n = DELTA[r2 * 4096 + d];
      u_n = (float)XC[r2 * 4096 + d];
      z_n = (float)XZ[r2 * 8192 + 4096 + d];
      const float* Bp2 = XDBL + r2 * 256 + 128;
#pragma unroll
      for (int q = 0; q < 4; ++q) {
        Bn[q] = *(const floatx4*)(Bp2 + q * 4);
        Cn[q] = *(const floatx4*)(Bp2 + 16 + q * 4);
      }
    }
    const float du = dlt * u;
    float y = 0.f;
#pragma unroll
    for (int q = 0; q < 4; ++q)
#pragma unroll
      for (int j = 0; j < 4; ++j) {
        const int n = q * 4 + j;
        const float dA = exp2f(dlt * A2[n]);  // exp(delta*A)
        st[n] = dA * st[n] + du * Bv[q][j];
        y += st[n] * Cv[q][j];
      }
    const float sig = 1.f / (1.f + __expf(-z));
    Y[row * 4096 + d] = (bf16)((y + Dd * u) * (z * sig));
    ++row;
    if (l < 1023) {
      dlt = dlt_n; u = u_n; z = z_n;
#pragma unroll
      for (int q = 0; q < 4; ++q) { Bv[q] = Bn[q]; Cv[q] = Cn[q]; }
    }
  }
#pragma unroll
  for (int n = 0; n < 16; ++n)
    lastOut[(size_t)b * 65536 + d * 16 + n] = st[n];
}

// ---------------------------------------------------------------------------
// Workspace layout (bytes)
// ---------------------------------------------------------------------------
#define OFF_XZ 0UL                 // bf16 2048x8192
#define OFF_XC 33554432UL          // bf16 2048x4096
#define OFF_DELTA 50331648UL       // f32  2048x4096
#define OFF_Y 83886080UL           // bf16 2048x4096
#define OFF_XDBL 100663296UL       // f32  2048x256
#define OFF_DT 102760448UL         // bf16 2048x128
#define OFF_WXPAD 103284736UL      // bf16 256x4096

extern "C" void kernel_launch(void* const* d_in, const int* in_sizes, int n_in,
                              void* d_out, int out_size, void* d_ws,
                              size_t ws_size, hipStream_t stream) {
  const float* hidden = (const float*)d_in[0];  // (2,1024,2048)
  const float* W_in = (const float*)d_in[1];    // (8192,2048)
  const float* conv_w = (const float*)d_in[2];  // (4096,4)
  const float* conv_b = (const float*)d_in[3];  // (4096,)
  const float* W_x = (const float*)d_in[4];     // (160,4096)
  const float* W_dt = (const float*)d_in[5];    // (4096,128)
  const float* b_dt = (const float*)d_in[6];    // (4096,)
  const float* A_log = (const float*)d_in[7];   // (4096,16)
  const float* Dvec = (const float*)d_in[8];    // (4096,)
  const float* W_out = (const float*)d_in[9];   // (2048,4096)
  const float* b_out = (const float*)d_in[10];  // (2048,)

  char* ws = (char*)d_ws;
  bf16* XZ = (bf16*)(ws + OFF_XZ);
  bf16* XC = (bf16*)(ws + OFF_XC);
  float* DELTA = (float*)(ws + OFF_DELTA);
  bf16* Y = (bf16*)(ws + OFF_Y);
  float* XDBL = (float*)(ws + OFF_XDBL);
  bf16* DT = (bf16*)(ws + OFF_DT);
  bf16* WXPAD = (bf16*)(ws + OFF_WXPAD);

  float* out = (float*)d_out;             // (2,1024,2048) = 4194304 f32
  float* out_conv = out + 4194304;        // (2,4096,4)    = 32768 f32
  float* out_last = out + 4227072;        // (2,4096,16)   = 131072 f32

  wxpad_prep<<<4096, 256, 0, stream>>>(W_x, WXPAD);
  hipMemsetAsync(XDBL, 0, 2048UL * 256 * 4, stream);

  // GEMM1: XZ(2048x8192 bf16) = hidden(2048x2048 f32) @ W_in^T(f32)
  gemm_bt<0, 1, 1><<<dim3(16, 64, 1), 256, 0, stream>>>(hidden, W_in, XZ,
                                                        nullptr, 2048, 8192,
                                                        2048);
  conv_kernel<<<32768, 256, 0, stream>>>(XZ, conv_w, conv_b, XC);
  convstate_kernel<<<128, 256, 0, stream>>>(XZ, out_conv);
  // GEMM2 (split-K=8, f32 atomics): XDBL(2048x256) = XC @ WXPAD^T
  gemm_bt<1, 0, 0><<<dim3(16, 2, 8), 256, 0, stream>>>(XC, WXPAD, XDBL, nullptr,
                                                       2048, 256, 4096);
  dtcast_kernel<<<1024, 256, 0, stream>>>(XDBL, DT);
  // GEMM_dt: DELTA(2048x4096 f32) = softplus(DT @ W_dt^T + b_dt)
  gemm_bt<2, 0, 1><<<dim3(16, 32, 1), 256, 0, stream>>>(DT, W_dt, DELTA, b_dt,
                                                        2048, 4096, 128);
  scan_kernel<<<128, 64, 0, stream>>>(DELTA, XC, XZ, XDBL, A_log, Dvec, Y,
                                      out_last);
  // GEMM3: out(2048x2048 f32) = Y @ W_out^T + b_out
  gemm_bt<3, 0, 1><<<dim3(16, 16, 1), 256, 0, stream>>>(Y, W_out, out, b_out,
                                                        2048, 2048, 4096);
}

// Round 4
// 694.554 us; speedup vs baseline: 1.6328x; 1.6328x over previous
//
#include <hip/hip_runtime.h>
#include <stdint.h>
#include <stddef.h>

typedef __bf16 bf16;
typedef __attribute__((ext_vector_type(8))) __bf16 bf16x8;
typedef __attribute__((ext_vector_type(4))) float floatx4;

#define GAS __attribute__((address_space(1)))
#define LAS __attribute__((address_space(3)))

__device__ __forceinline__ void async16(const void* g, void* l) {
  __builtin_amdgcn_global_load_lds((const GAS void*)g, (LAS void*)l, 16, 0, 0);
}

__device__ __forceinline__ bf16x8 cvt8(const float* p) {
  floatx4 a = *(const floatx4*)p;
  floatx4 b = *(const floatx4*)(p + 4);
  bf16x8 r;
  r[0] = (bf16)a[0]; r[1] = (bf16)a[1]; r[2] = (bf16)a[2]; r[3] = (bf16)a[3];
  r[4] = (bf16)b[0]; r[5] = (bf16)b[1]; r[6] = (bf16)b[2]; r[7] = (bf16)b[3];
  return r;
}

// ---------------------------------------------------------------------------
// Generic "bt" GEMM: C[M,N] = A[M,K] @ B[N,K]^T, row-major K-contig operands.
// AF/BF: f32 operand (VGPR load + cvt + ds_write staging) vs bf16 operand
// (async global_load_lds staging). 128x128 tile, BK=32, 256 thr,
// mfma_f32_16x16x32_bf16.
// EPI: 0 bf16 store | 1 f32 atomicAdd (split-K) | 2 f32 softplus(v+bias) |
//      3 f32 (v+bias)
// ---------------------------------------------------------------------------
template <int EPI, int AF, int BF>
__global__ __launch_bounds__(256, 2) void gemm_bt(
    const void* __restrict__ Aptr, const void* __restrict__ Bptr,
    void* __restrict__ Cout, const float* __restrict__ bias,
    int M, int N, int K) {
  __shared__ bf16 As[128 * 32];
  __shared__ bf16 Bs[128 * 32];
  const int tid = threadIdx.x;

  const int rowBase = blockIdx.x * 128;
  const int colBase = blockIdx.y * 128;
  const int kLen = K / gridDim.z;
  const int k0 = blockIdx.z * kLen;
  const int kIters = kLen / 32;

  const int sRow = tid >> 2;
  const int sCol = (tid & 3) << 3;
  const int wave = tid >> 6;
  const int lane = tid & 63;
  const int wm = (wave >> 1) << 6;  // 0 / 64
  const int wn = (wave & 1) << 6;   // 0 / 64
  const int lr = lane & 15;
  const int kg = lane >> 4;

  floatx4 acc[4][4] = {};

  for (int kt = 0; kt < kIters; ++kt) {
    const int kk = k0 + kt * 32;
    __syncthreads();  // prev iter's LDS reads done before overwrite
    if constexpr (AF) {
      const float* pa = (const float*)Aptr + (size_t)(rowBase + sRow) * K + kk + sCol;
      *(bf16x8*)&As[tid * 8] = cvt8(pa);
      *(bf16x8*)&As[2048 + tid * 8] = cvt8(pa + (size_t)64 * K);
    } else {
      const bf16* pa = (const bf16*)Aptr + (size_t)(rowBase + sRow) * K + kk + sCol;
      async16(pa, &As[tid * 8]);
      async16(pa + (size_t)64 * K, &As[2048 + tid * 8]);
    }
    if constexpr (BF) {
      const float* pb = (const float*)Bptr + (size_t)(colBase + sRow) * K + kk + sCol;
      *(bf16x8*)&Bs[tid * 8] = cvt8(pb);
      *(bf16x8*)&Bs[2048 + tid * 8] = cvt8(pb + (size_t)64 * K);
    } else {
      const bf16* pb = (const bf16*)Bptr + (size_t)(colBase + sRow) * K + kk + sCol;
      async16(pb, &Bs[tid * 8]);
      async16(pb + (size_t)64 * K, &Bs[2048 + tid * 8]);
    }
    __syncthreads();  // staging complete -> tile visible

    bf16x8 af[4], bg[4];
#pragma unroll
    for (int i = 0; i < 4; ++i)
      af[i] = *(const bf16x8*)&As[(wm + i * 16 + lr) * 32 + kg * 8];
#pragma unroll
    for (int j = 0; j < 4; ++j)
      bg[j] = *(const bf16x8*)&Bs[(wn + j * 16 + lr) * 32 + kg * 8];
#pragma unroll
    for (int i = 0; i < 4; ++i)
#pragma unroll
      for (int j = 0; j < 4; ++j)
        acc[i][j] = __builtin_amdgcn_mfma_f32_16x16x32_bf16(af[i], bg[j],
                                                            acc[i][j], 0, 0, 0);
  }

  // epilogue: C/D layout col = lane&15, row = (lane>>4)*4 + reg  [m89]
#pragma unroll
  for (int i = 0; i < 4; ++i) {
#pragma unroll
    for (int j = 0; j < 4; ++j) {
      const int col = colBase + wn + j * 16 + lr;
      float bv = 0.f;
      if constexpr (EPI == 2 || EPI == 3) bv = bias[col];
#pragma unroll
      for (int r = 0; r < 4; ++r) {
        const int row = rowBase + wm + i * 16 + kg * 4 + r;
        const size_t idx = (size_t)row * N + col;
        float v = acc[i][j][r];
        if constexpr (EPI == 0) {
          ((bf16*)Cout)[idx] = (bf16)v;
        } else if constexpr (EPI == 1) {
          atomicAdd((float*)Cout + idx, v);
        } else if constexpr (EPI == 2) {
          v += bv;  // softplus = max(v,0) + log1p(exp(-|v|))
          v = fmaxf(v, 0.f) + log1pf(__expf(-fabsf(v)));
          ((float*)Cout)[idx] = v;
        } else {
          ((float*)Cout)[idx] = v + bv;
        }
      }
    }
  }
}

// W_x (160x4096 f32) -> WXPAD (256x4096 bf16), zero rows >= 160.
__global__ void wxpad_prep(const float* __restrict__ Wx,
                           bf16* __restrict__ WXPAD) {
  const int idx = blockIdx.x * 256 + threadIdx.x;
  const int row = idx >> 12;
  WXPAD[idx] = (row < 160) ? (bf16)Wx[idx] : (bf16)0.f;
}

// Depthwise causal conv (K=4) + bias + SiLU over XZ's x half.
__global__ void conv_kernel(const bf16* __restrict__ XZ,
                            const float* __restrict__ conv_w,
                            const float* __restrict__ conv_b,
                            bf16* __restrict__ XC) {
  const int idx = blockIdx.x * 256 + threadIdx.x;  // 2048*4096
  const int d = idx & 4095;
  const int row = idx >> 12;
  const int l = row & 1023;
  float acc = conv_b[d];
#pragma unroll
  for (int k = 0; k < 4; ++k) {
    if (l - 3 + k >= 0)
      acc += conv_w[d * 4 + k] * (float)XZ[(size_t)(row - 3 + k) * 8192 + d];
  }
  const float s = acc / (1.f + __expf(-acc));
  XC[(size_t)row * 4096 + d] = (bf16)s;
}

// conv_state output (f32): out[b,d,k] = x[b, 1020+k, d]
__global__ void convstate_kernel(const bf16* __restrict__ XZ,
                                 float* __restrict__ outConv) {
  const int idx = blockIdx.x * 256 + threadIdx.x;  // 32768
  const int k = idx & 3;
  const int d = (idx >> 2) & 4095;
  const int b = idx >> 14;
  outConv[idx] = (float)XZ[(size_t)(b * 1024 + 1020 + k) * 8192 + d];
}

// dt columns of XDBL (f32 2048x256) -> DT bf16 (2048x128)
__global__ void dtcast_kernel(const float* __restrict__ XDBL,
                              bf16* __restrict__ DT) {
  const int idx = blockIdx.x * 256 + threadIdx.x;
  const int row = idx >> 7;
  const int r = idx & 127;
  DT[idx] = (bf16)XDBL[row * 256 + r];
}

// ---------------------------------------------------------------------------
// Chunked parallel scan. L=1024 split into 32 chunks of 32.
// st_{t+1} = dA_t st_t + du_t B_t is linear -> chunk summary (P=prod dA,
// L=state from 0 init). phase1: per-chunk P,L (bf16 - full f32 exponent
// range). phase2: sequential combine over 32 chunks -> per-chunk incoming
// state In (f32) + final state to d_out. phase3: replay chunk from In,
// y = C.st, fuse (y+D*u)*silu(z) -> Y bf16.
// ---------------------------------------------------------------------------
#define NCH 32
#define CLEN 32
#define LOG2E 1.44269504088896f

__global__ __launch_bounds__(256) void scan_phase1(
    const float* __restrict__ DELTA, const bf16* __restrict__ XC,
    const float* __restrict__ XDBL, const float* __restrict__ A_log,
    bf16* __restrict__ P, bf16* __restrict__ Lc) {
  const int bd = blockIdx.x * 256 + threadIdx.x;  // 0..8191
  const int c = blockIdx.y;
  const int b = bd >> 12;
  const int d = bd & 4095;
  float A2[16], st[16], p[16];
#pragma unroll
  for (int n = 0; n < 16; ++n) {
    A2[n] = -__expf(A_log[d * 16 + n]) * LOG2E;
    st[n] = 0.f;
    p[n] = 1.f;
  }
  size_t row = (size_t)b * 1024 + (size_t)c * CLEN;
  for (int t = 0; t < CLEN; ++t, ++row) {
    const float dlt = DELTA[row * 4096 + d];
    const float u = (float)XC[row * 4096 + d];
    const float* __restrict__ Bp = XDBL + row * 256 + 128;  // wave-uniform
    const float du = dlt * u;
#pragma unroll
    for (int n = 0; n < 16; ++n) {
      const float dA = exp2f(dlt * A2[n]);
      st[n] = dA * st[n] + du * Bp[n];
      p[n] *= dA;
    }
  }
  const size_t o = ((size_t)c * 8192 + bd) * 16;
  bf16x8 pk[2], lk[2];
#pragma unroll
  for (int n = 0; n < 16; ++n) {
    pk[n >> 3][n & 7] = (bf16)p[n];
    lk[n >> 3][n & 7] = (bf16)st[n];
  }
  *(bf16x8*)&P[o] = pk[0];
  *(bf16x8*)&P[o + 8] = pk[1];
  *(bf16x8*)&Lc[o] = lk[0];
  *(bf16x8*)&Lc[o + 8] = lk[1];
}

__global__ __launch_bounds__(256) void scan_phase2(
    const bf16* __restrict__ P, const bf16* __restrict__ Lc,
    float* __restrict__ In, float* __restrict__ lastOut) {
  const int bd = blockIdx.x * 256 + threadIdx.x;  // 0..8191
  float st[16] = {};
  for (int c = 0; c < NCH; ++c) {
    const size_t o = ((size_t)c * 8192 + bd) * 16;
    const bf16x8 p0 = *(const bf16x8*)&P[o];
    const bf16x8 p1 = *(const bf16x8*)&P[o + 8];
    const bf16x8 l0 = *(const bf16x8*)&Lc[o];
    const bf16x8 l1 = *(const bf16x8*)&Lc[o + 8];
    floatx4 w[4];
#pragma unroll
    for (int n = 0; n < 16; ++n) w[n >> 2][n & 3] = st[n];
#pragma unroll
    for (int q = 0; q < 4; ++q) *(floatx4*)&In[o + q * 4] = w[q];
#pragma unroll
    for (int n = 0; n < 8; ++n) {
      st[n] = (float)p0[n] * st[n] + (float)l0[n];
      st[8 + n] = (float)p1[n] * st[8 + n] + (float)l1[n];
    }
  }
  const int b = bd >> 12;
  const int d = bd & 4095;
#pragma unroll
  for (int n = 0; n < 16; ++n)
    lastOut[(size_t)b * 65536 + d * 16 + n] = st[n];
}

__global__ __launch_bounds__(256) void scan_phase3(
    const float* __restrict__ DELTA, const bf16* __restrict__ XC,
    const bf16* __restrict__ XZ, const float* __restrict__ XDBL,
    const float* __restrict__ A_log, const float* __restrict__ Dp,
    const float* __restrict__ In, bf16* __restrict__ Y) {
  const int bd = blockIdx.x * 256 + threadIdx.x;
  const int c = blockIdx.y;
  const int b = bd >> 12;
  const int d = bd & 4095;
  float A2[16], st[16];
  const size_t o = ((size_t)c * 8192 + bd) * 16;
#pragma unroll
  for (int q = 0; q < 4; ++q) {
    const floatx4 v = *(const floatx4*)&In[o + q * 4];
#pragma unroll
    for (int j = 0; j < 4; ++j) st[q * 4 + j] = v[j];
  }
#pragma unroll
  for (int n = 0; n < 16; ++n)
    A2[n] = -__expf(A_log[d * 16 + n]) * LOG2E;
  const float Dd = Dp[d];
  size_t row = (size_t)b * 1024 + (size_t)c * CLEN;
  for (int t = 0; t < CLEN; ++t, ++row) {
    const float dlt = DELTA[row * 4096 + d];
    const float u = (float)XC[row * 4096 + d];
    const float z = (float)XZ[row * 8192 + 4096 + d];
    const float* __restrict__ Bp = XDBL + row * 256 + 128;
    const float du = dlt * u;
    float y = 0.f;
#pragma unroll
    for (int n = 0; n < 16; ++n) {
      const float dA = exp2f(dlt * A2[n]);
      st[n] = dA * st[n] + du * Bp[n];
      y += st[n] * Bp[16 + n];
    }
    const float sig = 1.f / (1.f + __expf(-z));
    Y[row * 4096 + d] = (bf16)((y + Dd * u) * (z * sig));
  }
}

// ---------------------------------------------------------------------------
// Workspace layout (bytes)
// ---------------------------------------------------------------------------
#define OFF_XZ 0UL                 // bf16 2048x8192
#define OFF_XC 33554432UL          // bf16 2048x4096
#define OFF_DELTA 50331648UL       // f32  2048x4096
#define OFF_Y 83886080UL           // bf16 2048x4096
#define OFF_XDBL 100663296UL       // f32  2048x256
#define OFF_DT 102760448UL         // bf16 2048x128
#define OFF_WXPAD 103284736UL      // bf16 256x4096
#define OFF_P 105381888UL          // bf16 32x8192x16 = 8388608
#define OFF_L 113770496UL          // bf16 32x8192x16 = 8388608  (end 116.5MB)

extern "C" void kernel_launch(void* const* d_in, const int* in_sizes, int n_in,
                              void* d_out, int out_size, void* d_ws,
                              size_t ws_size, hipStream_t stream) {
  const float* hidden = (const float*)d_in[0];
  const float* W_in = (const float*)d_in[1];
  const float* conv_w = (const float*)d_in[2];
  const float* conv_b = (const float*)d_in[3];
  const float* W_x = (const float*)d_in[4];
  const float* W_dt = (const float*)d_in[5];
  const float* b_dt = (const float*)d_in[6];
  const float* A_log = (const float*)d_in[7];
  const float* Dvec = (const float*)d_in[8];
  const float* W_out = (const float*)d_in[9];
  const float* b_out = (const float*)d_in[10];

  char* ws = (char*)d_ws;
  bf16* XZ = (bf16*)(ws + OFF_XZ);
  bf16* XC = (bf16*)(ws + OFF_XC);
  float* DELTA = (float*)(ws + OFF_DELTA);
  bf16* Y = (bf16*)(ws + OFF_Y);
  float* XDBL = (float*)(ws + OFF_XDBL);
  bf16* DT = (bf16*)(ws + OFF_DT);
  bf16* WXPAD = (bf16*)(ws + OFF_WXPAD);
  bf16* P = (bf16*)(ws + OFF_P);
  bf16* Lc = (bf16*)(ws + OFF_L);

  float* out = (float*)d_out;             // (2,1024,2048) = 4194304 f32
  float* out_conv = out + 4194304;        // (2,4096,4)
  float* out_last = out + 4227072;        // (2,4096,16)
  // In (f32, 32x8192x16 = 16777216 B) parks in the `out` region: written by
  // phase2, read by phase3, then fully overwritten by GEMM3. Same-stream
  // ordering makes this safe.
  float* In = out;

  wxpad_prep<<<4096, 256, 0, stream>>>(W_x, WXPAD);
  hipMemsetAsync(XDBL, 0, 2048UL * 256 * 4, stream);

  // GEMM1: XZ(2048x8192 bf16) = hidden(f32) @ W_in^T(f32)
  gemm_bt<0, 1, 1><<<dim3(16, 64, 1), 256, 0, stream>>>(hidden, W_in, XZ,
                                                        nullptr, 2048, 8192,
                                                        2048);
  conv_kernel<<<32768, 256, 0, stream>>>(XZ, conv_w, conv_b, XC);
  convstate_kernel<<<128, 256, 0, stream>>>(XZ, out_conv);
  // GEMM2 (split-K=8, f32 atomics): XDBL(2048x256) = XC @ WXPAD^T
  gemm_bt<1, 0, 0><<<dim3(16, 2, 8), 256, 0, stream>>>(XC, WXPAD, XDBL, nullptr,
                                                       2048, 256, 4096);
  dtcast_kernel<<<1024, 256, 0, stream>>>(XDBL, DT);
  // GEMM_dt: DELTA(2048x4096 f32) = softplus(DT @ W_dt^T + b_dt)
  gemm_bt<2, 0, 1><<<dim3(16, 32, 1), 256, 0, stream>>>(DT, W_dt, DELTA, b_dt,
                                                        2048, 4096, 128);
  // chunked scan
  scan_phase1<<<dim3(32, NCH), 256, 0, stream>>>(DELTA, XC, XDBL, A_log, P, Lc);
  scan_phase2<<<32, 256, 0, stream>>>(P, Lc, In, out_last);
  scan_phase3<<<dim3(32, NCH), 256, 0, stream>>>(DELTA, XC, XZ, XDBL, A_log,
                                                 Dvec, In, Y);
  // GEMM3: out(2048x2048 f32) = Y @ W_out^T + b_out
  gemm_bt<3, 0, 1><<<dim3(16, 16, 1), 256, 0, stream>>>(Y, W_out, out, b_out,
                                                        2048, 2048, 4096);
}

// Round 5
// 572.456 us; speedup vs baseline: 1.9810x; 1.2133x over previous
//
#include <hip/hip_runtime.h>
#include <stdint.h>
#include <stddef.h>

typedef __bf16 bf16;
typedef __attribute__((ext_vector_type(8))) __bf16 bf16x8;
typedef __attribute__((ext_vector_type(4))) float floatx4;

#define GAS __attribute__((address_space(1)))
#define LAS __attribute__((address_space(3)))

__device__ __forceinline__ void async16(const void* g, void* l) {
  __builtin_amdgcn_global_load_lds((const GAS void*)g, (LAS void*)l, 16, 0, 0);
}

__device__ __forceinline__ bf16x8 cvt8(const float* p) {
  floatx4 a = *(const floatx4*)p;
  floatx4 b = *(const floatx4*)(p + 4);
  bf16x8 r;
  r[0] = (bf16)a[0]; r[1] = (bf16)a[1]; r[2] = (bf16)a[2]; r[3] = (bf16)a[3];
  r[4] = (bf16)b[0]; r[5] = (bf16)b[1]; r[6] = (bf16)b[2]; r[7] = (bf16)b[3];
  return r;
}

// ---------------------------------------------------------------------------
// Generic "bt" GEMM: C[M,N] = A[M,K] @ B[N,K]^T, row-major K-contig operands.
// AF/BF: f32 operand (VGPR load + cvt + ds_write staging) vs bf16 operand
// (async global_load_lds staging). 128x128 tile, BK=32, 256 thr,
// mfma_f32_16x16x32_bf16.
// EPI: 0 bf16 store | 1 f32 atomicAdd (split-K) | 2 f32 softplus(v+bias) |
//      3 f32 (v+bias)
// ---------------------------------------------------------------------------
template <int EPI, int AF, int BF>
__global__ __launch_bounds__(256, 2) void gemm_bt(
    const void* __restrict__ Aptr, const void* __restrict__ Bptr,
    void* __restrict__ Cout, const float* __restrict__ bias,
    int M, int N, int K) {
  __shared__ bf16 As[128 * 32];
  __shared__ bf16 Bs[128 * 32];
  const int tid = threadIdx.x;

  const int rowBase = blockIdx.x * 128;
  const int colBase = blockIdx.y * 128;
  const int kLen = K / gridDim.z;
  const int k0 = blockIdx.z * kLen;
  const int kIters = kLen / 32;

  const int sRow = tid >> 2;
  const int sCol = (tid & 3) << 3;
  const int wave = tid >> 6;
  const int lane = tid & 63;
  const int wm = (wave >> 1) << 6;  // 0 / 64
  const int wn = (wave & 1) << 6;   // 0 / 64
  const int lr = lane & 15;
  const int kg = lane >> 4;

  floatx4 acc[4][4] = {};

  for (int kt = 0; kt < kIters; ++kt) {
    const int kk = k0 + kt * 32;
    __syncthreads();  // prev iter's LDS reads done before overwrite
    if constexpr (AF) {
      const float* pa = (const float*)Aptr + (size_t)(rowBase + sRow) * K + kk + sCol;
      *(bf16x8*)&As[tid * 8] = cvt8(pa);
      *(bf16x8*)&As[2048 + tid * 8] = cvt8(pa + (size_t)64 * K);
    } else {
      const bf16* pa = (const bf16*)Aptr + (size_t)(rowBase + sRow) * K + kk + sCol;
      async16(pa, &As[tid * 8]);
      async16(pa + (size_t)64 * K, &As[2048 + tid * 8]);
    }
    if constexpr (BF) {
      const float* pb = (const float*)Bptr + (size_t)(colBase + sRow) * K + kk + sCol;
      *(bf16x8*)&Bs[tid * 8] = cvt8(pb);
      *(bf16x8*)&Bs[2048 + tid * 8] = cvt8(pb + (size_t)64 * K);
    } else {
      const bf16* pb = (const bf16*)Bptr + (size_t)(colBase + sRow) * K + kk + sCol;
      async16(pb, &Bs[tid * 8]);
      async16(pb + (size_t)64 * K, &Bs[2048 + tid * 8]);
    }
    __syncthreads();  // staging complete -> tile visible

    bf16x8 af[4], bg[4];
#pragma unroll
    for (int i = 0; i < 4; ++i)
      af[i] = *(const bf16x8*)&As[(wm + i * 16 + lr) * 32 + kg * 8];
#pragma unroll
    for (int j = 0; j < 4; ++j)
      bg[j] = *(const bf16x8*)&Bs[(wn + j * 16 + lr) * 32 + kg * 8];
#pragma unroll
    for (int i = 0; i < 4; ++i)
#pragma unroll
      for (int j = 0; j < 4; ++j)
        acc[i][j] = __builtin_amdgcn_mfma_f32_16x16x32_bf16(af[i], bg[j],
                                                            acc[i][j], 0, 0, 0);
  }

  // epilogue: C/D layout col = lane&15, row = (lane>>4)*4 + reg  [m89]
#pragma unroll
  for (int i = 0; i < 4; ++i) {
#pragma unroll
    for (int j = 0; j < 4; ++j) {
      const int col = colBase + wn + j * 16 + lr;
      float bv = 0.f;
      if constexpr (EPI == 2 || EPI == 3) bv = bias[col];
#pragma unroll
      for (int r = 0; r < 4; ++r) {
        const int row = rowBase + wm + i * 16 + kg * 4 + r;
        const size_t idx = (size_t)row * N + col;
        float v = acc[i][j][r];
        if constexpr (EPI == 0) {
          ((bf16*)Cout)[idx] = (bf16)v;
        } else if constexpr (EPI == 1) {
          atomicAdd((float*)Cout + idx, v);
        } else if constexpr (EPI == 2) {
          v += bv;  // softplus = max(v,0) + log1p(exp(-|v|))
          v = fmaxf(v, 0.f) + log1pf(__expf(-fabsf(v)));
          ((float*)Cout)[idx] = v;
        } else {
          ((float*)Cout)[idx] = v + bv;
        }
      }
    }
  }
}

// ---------------------------------------------------------------------------
// Fused f32->bf16 pre-cast of all GEMM operand inputs:
// hidden (4194304) | W_in (16777216) | W_dt (524288) | W_out (8388608)
// ---------------------------------------------------------------------------
#define CR0 4194304UL
#define CR1 20971520UL
#define CR2 21495808UL
#define CR3 29884416UL
__global__ __launch_bounds__(256) void cast_all(
    const float* __restrict__ h, const float* __restrict__ wi,
    const float* __restrict__ wd, const float* __restrict__ wo,
    bf16* __restrict__ hb, bf16* __restrict__ wib, bf16* __restrict__ wdb,
    bf16* __restrict__ wob) {
  const size_t g = ((size_t)blockIdx.x * 256 + threadIdx.x) * 8;
  const float* src;
  bf16* dst;
  size_t off;
  if (g < CR0) { src = h; dst = hb; off = g; }
  else if (g < CR1) { src = wi; dst = wib; off = g - CR0; }
  else if (g < CR2) { src = wd; dst = wdb; off = g - CR1; }
  else { src = wo; dst = wob; off = g - CR2; }
  *(bf16x8*)&dst[off] = cvt8(&src[off]);
}

// W_x (160x4096 f32) -> WXPAD (256x4096 bf16), zero rows >= 160.
__global__ void wxpad_prep(const float* __restrict__ Wx,
                           bf16* __restrict__ WXPAD) {
  const int idx = blockIdx.x * 256 + threadIdx.x;
  const int row = idx >> 12;
  WXPAD[idx] = (row < 160) ? (bf16)Wx[idx] : (bf16)0.f;
}

// Depthwise causal conv (K=4) + bias + SiLU over XZ's x half.
__global__ void conv_kernel(const bf16* __restrict__ XZ,
                            const float* __restrict__ conv_w,
                            const float* __restrict__ conv_b,
                            bf16* __restrict__ XC) {
  const int idx = blockIdx.x * 256 + threadIdx.x;  // 2048*4096
  const int d = idx & 4095;
  const int row = idx >> 12;
  const int l = row & 1023;
  float acc = conv_b[d];
#pragma unroll
  for (int k = 0; k < 4; ++k) {
    if (l - 3 + k >= 0)
      acc += conv_w[d * 4 + k] * (float)XZ[(size_t)(row - 3 + k) * 8192 + d];
  }
  const float s = acc / (1.f + __expf(-acc));
  XC[(size_t)row * 4096 + d] = (bf16)s;
}

// conv_state output (f32): out[b,d,k] = x[b, 1020+k, d]
__global__ void convstate_kernel(const bf16* __restrict__ XZ,
                                 float* __restrict__ outConv) {
  const int idx = blockIdx.x * 256 + threadIdx.x;  // 32768
  const int k = idx & 3;
  const int d = (idx >> 2) & 4095;
  const int b = idx >> 14;
  outConv[idx] = (float)XZ[(size_t)(b * 1024 + 1020 + k) * 8192 + d];
}

// dt columns of XDBL (f32 2048x256) -> DT bf16 (2048x128)
__global__ void dtcast_kernel(const float* __restrict__ XDBL,
                              bf16* __restrict__ DT) {
  const int idx = blockIdx.x * 256 + threadIdx.x;
  const int row = idx >> 7;
  const int r = idx & 127;
  DT[idx] = (bf16)XDBL[row * 256 + r];
}

// ---------------------------------------------------------------------------
// Chunked parallel scan (32 chunks of 32). phase1: per-chunk (P=prod dA,
// L=state from 0). phase2: sequential combine -> per-chunk incoming state In
// (f32) + final state out. phase3: replay chunk from In, fuse epilogue.
// ---------------------------------------------------------------------------
#define NCH 32
#define CLEN 32
#define LOG2E 1.44269504088896f

__global__ __launch_bounds__(256) void scan_phase1(
    const float* __restrict__ DELTA, const bf16* __restrict__ XC,
    const float* __restrict__ XDBL, const float* __restrict__ A_log,
    bf16* __restrict__ P, bf16* __restrict__ Lc) {
  const int bd = blockIdx.x * 256 + threadIdx.x;  // 0..8191
  const int c = blockIdx.y;
  const int b = bd >> 12;
  const int d = bd & 4095;
  float A2[16], st[16], p[16];
#pragma unroll
  for (int n = 0; n < 16; ++n) {
    A2[n] = -__expf(A_log[d * 16 + n]) * LOG2E;
    st[n] = 0.f;
    p[n] = 1.f;
  }
  size_t row = (size_t)b * 1024 + (size_t)c * CLEN;
  for (int t = 0; t < CLEN; ++t, ++row) {
    const float dlt = DELTA[row * 4096 + d];
    const float u = (float)XC[row * 4096 + d];
    const float* __restrict__ Bp = XDBL + row * 256 + 128;  // wave-uniform
    const float du = dlt * u;
#pragma unroll
    for (int n = 0; n < 16; ++n) {
      const float dA = exp2f(dlt * A2[n]);
      st[n] = dA * st[n] + du * Bp[n];
      p[n] *= dA;
    }
  }
  const size_t o = ((size_t)c * 8192 + bd) * 16;
  bf16x8 pk[2], lk[2];
#pragma unroll
  for (int n = 0; n < 16; ++n) {
    pk[n >> 3][n & 7] = (bf16)p[n];
    lk[n >> 3][n & 7] = (bf16)st[n];
  }
  *(bf16x8*)&P[o] = pk[0];
  *(bf16x8*)&P[o + 8] = pk[1];
  *(bf16x8*)&Lc[o] = lk[0];
  *(bf16x8*)&Lc[o + 8] = lk[1];
}

__global__ __launch_bounds__(256) void scan_phase2(
    const bf16* __restrict__ P, const bf16* __restrict__ Lc,
    float* __restrict__ In, float* __restrict__ lastOut) {
  const int bd = blockIdx.x * 256 + threadIdx.x;  // 0..8191
  float st[16] = {};
  for (int c = 0; c < NCH; ++c) {
    const size_t o = ((size_t)c * 8192 + bd) * 16;
    const bf16x8 p0 = *(const bf16x8*)&P[o];
    const bf16x8 p1 = *(const bf16x8*)&P[o + 8];
    const bf16x8 l0 = *(const bf16x8*)&Lc[o];
    const bf16x8 l1 = *(const bf16x8*)&Lc[o + 8];
    floatx4 w[4];
#pragma unroll
    for (int n = 0; n < 16; ++n) w[n >> 2][n & 3] = st[n];
#pragma unroll
    for (int q = 0; q < 4; ++q) *(floatx4*)&In[o + q * 4] = w[q];
#pragma unroll
    for (int n = 0; n < 8; ++n) {
      st[n] = (float)p0[n] * st[n] + (float)l0[n];
      st[8 + n] = (float)p1[n] * st[8 + n] + (float)l1[n];
    }
  }
  const int b = bd >> 12;
  const int d = bd & 4095;
#pragma unroll
  for (int n = 0; n < 16; ++n)
    lastOut[(size_t)b * 65536 + d * 16 + n] = st[n];
}

__global__ __launch_bounds__(256) void scan_phase3(
    const float* __restrict__ DELTA, const bf16* __restrict__ XC,
    const bf16* __restrict__ XZ, const float* __restrict__ XDBL,
    const float* __restrict__ A_log, const float* __restrict__ Dp,
    const float* __restrict__ In, bf16* __restrict__ Y) {
  const int bd = blockIdx.x * 256 + threadIdx.x;
  const int c = blockIdx.y;
  const int b = bd >> 12;
  const int d = bd & 4095;
  float A2[16], st[16];
  const size_t o = ((size_t)c * 8192 + bd) * 16;
#pragma unroll
  for (int q = 0; q < 4; ++q) {
    const floatx4 v = *(const floatx4*)&In[o + q * 4];
#pragma unroll
    for (int j = 0; j < 4; ++j) st[q * 4 + j] = v[j];
  }
#pragma unroll
  for (int n = 0; n < 16; ++n)
    A2[n] = -__expf(A_log[d * 16 + n]) * LOG2E;
  const float Dd = Dp[d];
  size_t row = (size_t)b * 1024 + (size_t)c * CLEN;
  for (int t = 0; t < CLEN; ++t, ++row) {
    const float dlt = DELTA[row * 4096 + d];
    const float u = (float)XC[row * 4096 + d];
    const float z = (float)XZ[row * 8192 + 4096 + d];
    const float* __restrict__ Bp = XDBL + row * 256 + 128;
    const float du = dlt * u;
    float y = 0.f;
#pragma unroll
    for (int n = 0; n < 16; ++n) {
      const float dA = exp2f(dlt * A2[n]);
      st[n] = dA * st[n] + du * Bp[n];
      y += st[n] * Bp[16 + n];
    }
    const float sig = 1.f / (1.f + __expf(-z));
    Y[row * 4096 + d] = (bf16)((y + Dd * u) * (z * sig));
  }
}

// ---------------------------------------------------------------------------
// Workspace layout (bytes)
// ---------------------------------------------------------------------------
#define OFF_XZ 0UL                 // bf16 2048x8192
#define OFF_XC 33554432UL          // bf16 2048x4096
#define OFF_DELTA 50331648UL       // f32  2048x4096
#define OFF_Y 83886080UL           // bf16 2048x4096
#define OFF_XDBL 100663296UL       // f32  2048x256
#define OFF_DT 102760448UL         // bf16 2048x128
#define OFF_WXPAD 103284736UL      // bf16 256x4096
#define OFF_P 105381888UL          // bf16 32x8192x16
#define OFF_L 113770496UL          // bf16 32x8192x16
#define OFF_HBF 122159104UL        // bf16 2048x2048   = 8388608
#define OFF_WINBF 130547712UL      // bf16 8192x2048   = 33554432
#define OFF_WDTBF 164102144UL      // bf16 4096x128    = 1048576
#define OFF_WOUTBF 165150720UL     // bf16 2048x4096   = 16777216
#define WS_NEED_CAST 181927936UL   // ~173.5 MB

extern "C" void kernel_launch(void* const* d_in, const int* in_sizes, int n_in,
                              void* d_out, int out_size, void* d_ws,
                              size_t ws_size, hipStream_t stream) {
  const float* hidden = (const float*)d_in[0];
  const float* W_in = (const float*)d_in[1];
  const float* conv_w = (const float*)d_in[2];
  const float* conv_b = (const float*)d_in[3];
  const float* W_x = (const float*)d_in[4];
  const float* W_dt = (const float*)d_in[5];
  const float* b_dt = (const float*)d_in[6];
  const float* A_log = (const float*)d_in[7];
  const float* Dvec = (const float*)d_in[8];
  const float* W_out = (const float*)d_in[9];
  const float* b_out = (const float*)d_in[10];

  char* ws = (char*)d_ws;
  bf16* XZ = (bf16*)(ws + OFF_XZ);
  bf16* XC = (bf16*)(ws + OFF_XC);
  float* DELTA = (float*)(ws + OFF_DELTA);
  bf16* Y = (bf16*)(ws + OFF_Y);
  float* XDBL = (float*)(ws + OFF_XDBL);
  bf16* DT = (bf16*)(ws + OFF_DT);
  bf16* WXPAD = (bf16*)(ws + OFF_WXPAD);
  bf16* P = (bf16*)(ws + OFF_P);
  bf16* Lc = (bf16*)(ws + OFF_L);

  float* out = (float*)d_out;             // (2,1024,2048) = 4194304 f32
  float* out_conv = out + 4194304;        // (2,4096,4)
  float* out_last = out + 4227072;        // (2,4096,16)
  // In (f32, 16.78 MB) parks in the `out` region: written by phase2, read by
  // phase3, then fully overwritten by GEMM3 (same-stream ordering).
  float* In = out;

  wxpad_prep<<<4096, 256, 0, stream>>>(W_x, WXPAD);
  hipMemsetAsync(XDBL, 0, 2048UL * 256 * 4, stream);

  const bool castOK = ws_size >= WS_NEED_CAST;
  if (castOK) {
    bf16* HBF = (bf16*)(ws + OFF_HBF);
    bf16* WINBF = (bf16*)(ws + OFF_WINBF);
    bf16* WDTBF = (bf16*)(ws + OFF_WDTBF);
    bf16* WOUTBF = (bf16*)(ws + OFF_WOUTBF);
    cast_all<<<14592, 256, 0, stream>>>(hidden, W_in, W_dt, W_out, HBF, WINBF,
                                        WDTBF, WOUTBF);
    // GEMM1: XZ = HBF @ WINBF^T (all-bf16 async staging)
    gemm_bt<0, 0, 0><<<dim3(16, 64, 1), 256, 0, stream>>>(HBF, WINBF, XZ,
                                                          nullptr, 2048, 8192,
                                                          2048);
    conv_kernel<<<32768, 256, 0, stream>>>(XZ, conv_w, conv_b, XC);
    convstate_kernel<<<128, 256, 0, stream>>>(XZ, out_conv);
    gemm_bt<1, 0, 0><<<dim3(16, 2, 8), 256, 0, stream>>>(XC, WXPAD, XDBL,
                                                         nullptr, 2048, 256,
                                                         4096);
    dtcast_kernel<<<1024, 256, 0, stream>>>(XDBL, DT);
    gemm_bt<2, 0, 0><<<dim3(16, 32, 1), 256, 0, stream>>>(DT, WDTBF, DELTA,
                                                          b_dt, 2048, 4096,
                                                          128);
    scan_phase1<<<dim3(32, NCH), 256, 0, stream>>>(DELTA, XC, XDBL, A_log, P,
                                                   Lc);
    scan_phase2<<<32, 256, 0, stream>>>(P, Lc, In, out_last);
    scan_phase3<<<dim3(32, NCH), 256, 0, stream>>>(DELTA, XC, XZ, XDBL, A_log,
                                                   Dvec, In, Y);
    gemm_bt<3, 0, 0><<<dim3(16, 16, 1), 256, 0, stream>>>(Y, WOUTBF, out, b_out,
                                                          2048, 2048, 4096);
  } else {
    // fallback: f32-staged GEMMs (round-4 path)
    gemm_bt<0, 1, 1><<<dim3(16, 64, 1), 256, 0, stream>>>(hidden, W_in, XZ,
                                                          nullptr, 2048, 8192,
                                                          2048);
    conv_kernel<<<32768, 256, 0, stream>>>(XZ, conv_w, conv_b, XC);
    convstate_kernel<<<128, 256, 0, stream>>>(XZ, out_conv);
    gemm_bt<1, 0, 0><<<dim3(16, 2, 8), 256, 0, stream>>>(XC, WXPAD, XDBL,
                                                         nullptr, 2048, 256,
                                                         4096);
    dtcast_kernel<<<1024, 256, 0, stream>>>(XDBL, DT);
    gemm_bt<2, 0, 1><<<dim3(16, 32, 1), 256, 0, stream>>>(DT, W_dt, DELTA, b_dt,
                                                          2048, 4096, 128);
    scan_phase1<<<dim3(32, NCH), 256, 0, stream>>>(DELTA, XC, XDBL, A_log, P,
                                                   Lc);
    scan_phase2<<<32, 256, 0, stream>>>(P, Lc, In, out_last);
    scan_phase3<<<dim3(32, NCH), 256, 0, stream>>>(DELTA, XC, XZ, XDBL, A_log,
                                                   Dvec, In, Y);
    gemm_bt<3, 0, 1><<<dim3(16, 16, 1), 256, 0, stream>>>(Y, W_out, out, b_out,
                                                          2048, 2048, 4096);
  }
}

// Round 6
// 544.705 us; speedup vs baseline: 2.0819x; 1.0509x over previous
//
#include <hip/hip_runtime.h>
#include <stdint.h>
#include <stddef.h>

typedef __bf16 bf16;
typedef __attribute__((ext_vector_type(8))) __bf16 bf16x8;
typedef __attribute__((ext_vector_type(4))) float floatx4;

#define GAS __attribute__((address_space(1)))
#define LAS __attribute__((address_space(3)))

__device__ __forceinline__ void async16(const void* g, void* l) {
  __builtin_amdgcn_global_load_lds((const GAS void*)g, (LAS void*)l, 16, 0, 0);
}

__device__ __forceinline__ bf16x8 cvt8(const float* p) {
  floatx4 a = *(const floatx4*)p;
  floatx4 b = *(const floatx4*)(p + 4);
  bf16x8 r;
  r[0] = (bf16)a[0]; r[1] = (bf16)a[1]; r[2] = (bf16)a[2]; r[3] = (bf16)a[3];
  r[4] = (bf16)b[0]; r[5] = (bf16)b[1]; r[6] = (bf16)b[2]; r[7] = (bf16)b[3];
  return r;
}

// ---------------------------------------------------------------------------
// Generic "bt" GEMM: C[M,N] = A[M,K] @ B[N,K]^T, row-major K-contig operands.
// AF/BF: f32 operand (VGPR load + cvt + ds_write staging) vs bf16 operand
// (async global_load_lds staging). 128x128 tile, BK=32, 256 thr,
// mfma_f32_16x16x32_bf16.
// EPI: 0 bf16 store | 1 f32 atomicAdd (split-K) | 2 bf16 softplus(v+bias)
//      (cheap __expf/__logf form — log1pf's ocml expansion cost ~90us in r5) |
//      3 f32 (v+bias)
// ---------------------------------------------------------------------------
template <int EPI, int AF, int BF>
__global__ __launch_bounds__(256, 2) void gemm_bt(
    const void* __restrict__ Aptr, const void* __restrict__ Bptr,
    void* __restrict__ Cout, const float* __restrict__ bias,
    int M, int N, int K) {
  __shared__ bf16 As[128 * 32];
  __shared__ bf16 Bs[128 * 32];
  const int tid = threadIdx.x;

  const int rowBase = blockIdx.x * 128;
  const int colBase = blockIdx.y * 128;
  const int kLen = K / gridDim.z;
  const int k0 = blockIdx.z * kLen;
  const int kIters = kLen / 32;

  const int sRow = tid >> 2;
  const int sCol = (tid & 3) << 3;
  const int wave = tid >> 6;
  const int lane = tid & 63;
  const int wm = (wave >> 1) << 6;  // 0 / 64
  const int wn = (wave & 1) << 6;   // 0 / 64
  const int lr = lane & 15;
  const int kg = lane >> 4;

  floatx4 acc[4][4] = {};

  for (int kt = 0; kt < kIters; ++kt) {
    const int kk = k0 + kt * 32;
    __syncthreads();  // prev iter's LDS reads done before overwrite
    if constexpr (AF) {
      const float* pa = (const float*)Aptr + (size_t)(rowBase + sRow) * K + kk + sCol;
      *(bf16x8*)&As[tid * 8] = cvt8(pa);
      *(bf16x8*)&As[2048 + tid * 8] = cvt8(pa + (size_t)64 * K);
    } else {
      const bf16* pa = (const bf16*)Aptr + (size_t)(rowBase + sRow) * K + kk + sCol;
      async16(pa, &As[tid * 8]);
      async16(pa + (size_t)64 * K, &As[2048 + tid * 8]);
    }
    if constexpr (BF) {
      const float* pb = (const float*)Bptr + (size_t)(colBase + sRow) * K + kk + sCol;
      *(bf16x8*)&Bs[tid * 8] = cvt8(pb);
      *(bf16x8*)&Bs[2048 + tid * 8] = cvt8(pb + (size_t)64 * K);
    } else {
      const bf16* pb = (const bf16*)Bptr + (size_t)(colBase + sRow) * K + kk + sCol;
      async16(pb, &Bs[tid * 8]);
      async16(pb + (size_t)64 * K, &Bs[2048 + tid * 8]);
    }
    __syncthreads();  // staging complete -> tile visible

    bf16x8 af[4], bg[4];
#pragma unroll
    for (int i = 0; i < 4; ++i)
      af[i] = *(const bf16x8*)&As[(wm + i * 16 + lr) * 32 + kg * 8];
#pragma unroll
    for (int j = 0; j < 4; ++j)
      bg[j] = *(const bf16x8*)&Bs[(wn + j * 16 + lr) * 32 + kg * 8];
#pragma unroll
    for (int i = 0; i < 4; ++i)
#pragma unroll
      for (int j = 0; j < 4; ++j)
        acc[i][j] = __builtin_amdgcn_mfma_f32_16x16x32_bf16(af[i], bg[j],
                                                            acc[i][j], 0, 0, 0);
  }

  // epilogue: C/D layout col = lane&15, row = (lane>>4)*4 + reg  [m89]
#pragma unroll
  for (int i = 0; i < 4; ++i) {
#pragma unroll
    for (int j = 0; j < 4; ++j) {
      const int col = colBase + wn + j * 16 + lr;
      float bv = 0.f;
      if constexpr (EPI == 2 || EPI == 3) bv = bias[col];
#pragma unroll
      for (int r = 0; r < 4; ++r) {
        const int row = rowBase + wm + i * 16 + kg * 4 + r;
        const size_t idx = (size_t)row * N + col;
        float v = acc[i][j][r];
        if constexpr (EPI == 0) {
          ((bf16*)Cout)[idx] = (bf16)v;
        } else if constexpr (EPI == 1) {
          atomicAdd((float*)Cout + idx, v);
        } else if constexpr (EPI == 2) {
          v += bv;
          // softplus = ln(1+e^v); for v>20, ln(1+e^v)==v to f32 precision.
          const float t = __expf(v);
          const float sp = (v > 20.f) ? v : __logf(1.f + t);
          ((bf16*)Cout)[idx] = (bf16)sp;
        } else {
          ((float*)Cout)[idx] = v + bv;
        }
      }
    }
  }
}

// ---------------------------------------------------------------------------
// Fused f32->bf16 pre-cast of all GEMM operand inputs:
// hidden (4194304) | W_in (16777216) | W_dt (524288) | W_out (8388608)
// ---------------------------------------------------------------------------
#define CR0 4194304UL
#define CR1 20971520UL
#define CR2 21495808UL
#define CR3 29884416UL
__global__ __launch_bounds__(256) void cast_all(
    const float* __restrict__ h, const float* __restrict__ wi,
    const float* __restrict__ wd, const float* __restrict__ wo,
    bf16* __restrict__ hb, bf16* __restrict__ wib, bf16* __restrict__ wdb,
    bf16* __restrict__ wob) {
  const size_t g = ((size_t)blockIdx.x * 256 + threadIdx.x) * 8;
  const float* src;
  bf16* dst;
  size_t off;
  if (g < CR0) { src = h; dst = hb; off = g; }
  else if (g < CR1) { src = wi; dst = wib; off = g - CR0; }
  else if (g < CR2) { src = wd; dst = wdb; off = g - CR1; }
  else { src = wo; dst = wob; off = g - CR2; }
  *(bf16x8*)&dst[off] = cvt8(&src[off]);
}

// W_x (160x4096 f32) -> WXPAD (256x4096 bf16), zero rows >= 160.
__global__ void wxpad_prep(const float* __restrict__ Wx,
                           bf16* __restrict__ WXPAD) {
  const int idx = blockIdx.x * 256 + threadIdx.x;
  const int row = idx >> 12;
  WXPAD[idx] = (row < 160) ? (bf16)Wx[idx] : (bf16)0.f;
}

// Depthwise causal conv (K=4) + bias + SiLU over XZ's x half.
__global__ void conv_kernel(const bf16* __restrict__ XZ,
                            const float* __restrict__ conv_w,
                            const float* __restrict__ conv_b,
                            bf16* __restrict__ XC) {
  const int idx = blockIdx.x * 256 + threadIdx.x;  // 2048*4096
  const int d = idx & 4095;
  const int row = idx >> 12;
  const int l = row & 1023;
  float acc = conv_b[d];
#pragma unroll
  for (int k = 0; k < 4; ++k) {
    if (l - 3 + k >= 0)
      acc += conv_w[d * 4 + k] * (float)XZ[(size_t)(row - 3 + k) * 8192 + d];
  }
  const float s = acc / (1.f + __expf(-acc));
  XC[(size_t)row * 4096 + d] = (bf16)s;
}

// conv_state output (f32): out[b,d,k] = x[b, 1020+k, d]
__global__ void convstate_kernel(const bf16* __restrict__ XZ,
                                 float* __restrict__ outConv) {
  const int idx = blockIdx.x * 256 + threadIdx.x;  // 32768
  const int k = idx & 3;
  const int d = (idx >> 2) & 4095;
  const int b = idx >> 14;
  outConv[idx] = (float)XZ[(size_t)(b * 1024 + 1020 + k) * 8192 + d];
}

// dt columns of XDBL (f32 2048x256) -> DT bf16 (2048x128)
__global__ void dtcast_kernel(const float* __restrict__ XDBL,
                              bf16* __restrict__ DT) {
  const int idx = blockIdx.x * 256 + threadIdx.x;
  const int row = idx >> 7;
  const int r = idx & 127;
  DT[idx] = (bf16)XDBL[row * 256 + r];
}

// ---------------------------------------------------------------------------
// Chunked parallel scan (32 chunks of 32). phase1: per-chunk (P=prod dA,
// L=state from 0). phase2: sequential combine -> per-chunk incoming state In
// (f32) + final state out. phase3: replay chunk from In, fuse epilogue.
// DELTA is bf16 (r6: halves GEMM_dt write + scan fetch).
// ---------------------------------------------------------------------------
#define NCH 32
#define CLEN 32
#define LOG2E 1.44269504088896f

__global__ __launch_bounds__(256) void scan_phase1(
    const bf16* __restrict__ DELTA, const bf16* __restrict__ XC,
    const float* __restrict__ XDBL, const float* __restrict__ A_log,
    bf16* __restrict__ P, bf16* __restrict__ Lc) {
  const int bd = blockIdx.x * 256 + threadIdx.x;  // 0..8191
  const int c = blockIdx.y;
  const int b = bd >> 12;
  const int d = bd & 4095;
  float A2[16], st[16], p[16];
#pragma unroll
  for (int n = 0; n < 16; ++n) {
    A2[n] = -__expf(A_log[d * 16 + n]) * LOG2E;
    st[n] = 0.f;
    p[n] = 1.f;
  }
  size_t row = (size_t)b * 1024 + (size_t)c * CLEN;
  for (int t = 0; t < CLEN; ++t, ++row) {
    const float dlt = (float)DELTA[row * 4096 + d];
    const float u = (float)XC[row * 4096 + d];
    const float* __restrict__ Bp = XDBL + row * 256 + 128;  // wave-uniform
    const float du = dlt * u;
#pragma unroll
    for (int n = 0; n < 16; ++n) {
      const float dA = exp2f(dlt * A2[n]);
      st[n] = dA * st[n] + du * Bp[n];
      p[n] *= dA;
    }
  }
  const size_t o = ((size_t)c * 8192 + bd) * 16;
  bf16x8 pk[2], lk[2];
#pragma unroll
  for (int n = 0; n < 16; ++n) {
    pk[n >> 3][n & 7] = (bf16)p[n];
    lk[n >> 3][n & 7] = (bf16)st[n];
  }
  *(bf16x8*)&P[o] = pk[0];
  *(bf16x8*)&P[o + 8] = pk[1];
  *(bf16x8*)&Lc[o] = lk[0];
  *(bf16x8*)&Lc[o + 8] = lk[1];
}

__global__ __launch_bounds__(256) void scan_phase2(
    const bf16* __restrict__ P, const bf16* __restrict__ Lc,
    float* __restrict__ In, float* __restrict__ lastOut) {
  const int bd = blockIdx.x * 256 + threadIdx.x;  // 0..8191
  float st[16] = {};
  for (int c = 0; c < NCH; ++c) {
    const size_t o = ((size_t)c * 8192 + bd) * 16;
    const bf16x8 p0 = *(const bf16x8*)&P[o];
    const bf16x8 p1 = *(const bf16x8*)&P[o + 8];
    const bf16x8 l0 = *(const bf16x8*)&Lc[o];
    const bf16x8 l1 = *(const bf16x8*)&Lc[o + 8];
    floatx4 w[4];
#pragma unroll
    for (int n = 0; n < 16; ++n) w[n >> 2][n & 3] = st[n];
#pragma unroll
    for (int q = 0; q < 4; ++q) *(floatx4*)&In[o + q * 4] = w[q];
#pragma unroll
    for (int n = 0; n < 8; ++n) {
      st[n] = (float)p0[n] * st[n] + (float)l0[n];
      st[8 + n] = (float)p1[n] * st[8 + n] + (float)l1[n];
    }
  }
  const int b = bd >> 12;
  const int d = bd & 4095;
#pragma unroll
  for (int n = 0; n < 16; ++n)
    lastOut[(size_t)b * 65536 + d * 16 + n] = st[n];
}

__global__ __launch_bounds__(256) void scan_phase3(
    const bf16* __restrict__ DELTA, const bf16* __restrict__ XC,
    const bf16* __restrict__ XZ, const float* __restrict__ XDBL,
    const float* __restrict__ A_log, const float* __restrict__ Dp,
    const float* __restrict__ In, bf16* __restrict__ Y) {
  const int bd = blockIdx.x * 256 + threadIdx.x;
  const int c = blockIdx.y;
  const int b = bd >> 12;
  const int d = bd & 4095;
  float A2[16], st[16];
  const size_t o = ((size_t)c * 8192 + bd) * 16;
#pragma unroll
  for (int q = 0; q < 4; ++q) {
    const floatx4 v = *(const floatx4*)&In[o + q * 4];
#pragma unroll
    for (int j = 0; j < 4; ++j) st[q * 4 + j] = v[j];
  }
#pragma unroll
  for (int n = 0; n < 16; ++n)
    A2[n] = -__expf(A_log[d * 16 + n]) * LOG2E;
  const float Dd = Dp[d];
  size_t row = (size_t)b * 1024 + (size_t)c * CLEN;
  for (int t = 0; t < CLEN; ++t, ++row) {
    const float dlt = (float)DELTA[row * 4096 + d];
    const float u = (float)XC[row * 4096 + d];
    const float z = (float)XZ[row * 8192 + 4096 + d];
    const float* __restrict__ Bp = XDBL + row * 256 + 128;
    const float du = dlt * u;
    float y = 0.f;
#pragma unroll
    for (int n = 0; n < 16; ++n) {
      const float dA = exp2f(dlt * A2[n]);
      st[n] = dA * st[n] + du * Bp[n];
      y += st[n] * Bp[16 + n];
    }
    const float sig = 1.f / (1.f + __expf(-z));
    Y[row * 4096 + d] = (bf16)((y + Dd * u) * (z * sig));
  }
}

// ---------------------------------------------------------------------------
// Workspace layout (bytes) — DELTA now bf16 (uses half its slot)
// ---------------------------------------------------------------------------
#define OFF_XZ 0UL                 // bf16 2048x8192
#define OFF_XC 33554432UL          // bf16 2048x4096
#define OFF_DELTA 50331648UL       // bf16 2048x4096 (slot sized for f32)
#define OFF_Y 83886080UL           // bf16 2048x4096
#define OFF_XDBL 100663296UL       // f32  2048x256
#define OFF_DT 102760448UL         // bf16 2048x128
#define OFF_WXPAD 103284736UL      // bf16 256x4096
#define OFF_P 105381888UL          // bf16 32x8192x16
#define OFF_L 113770496UL          // bf16 32x8192x16
#define OFF_HBF 122159104UL        // bf16 2048x2048
#define OFF_WINBF 130547712UL      // bf16 8192x2048
#define OFF_WDTBF 164102144UL      // bf16 4096x128
#define OFF_WOUTBF 165150720UL     // bf16 2048x4096
#define WS_NEED_CAST 181927936UL   // ~173.5 MB

extern "C" void kernel_launch(void* const* d_in, const int* in_sizes, int n_in,
                              void* d_out, int out_size, void* d_ws,
                              size_t ws_size, hipStream_t stream) {
  const float* hidden = (const float*)d_in[0];
  const float* W_in = (const float*)d_in[1];
  const float* conv_w = (const float*)d_in[2];
  const float* conv_b = (const float*)d_in[3];
  const float* W_x = (const float*)d_in[4];
  const float* W_dt = (const float*)d_in[5];
  const float* b_dt = (const float*)d_in[6];
  const float* A_log = (const float*)d_in[7];
  const float* Dvec = (const float*)d_in[8];
  const float* W_out = (const float*)d_in[9];
  const float* b_out = (const float*)d_in[10];

  char* ws = (char*)d_ws;
  bf16* XZ = (bf16*)(ws + OFF_XZ);
  bf16* XC = (bf16*)(ws + OFF_XC);
  bf16* DELTA = (bf16*)(ws + OFF_DELTA);
  bf16* Y = (bf16*)(ws + OFF_Y);
  float* XDBL = (float*)(ws + OFF_XDBL);
  bf16* DT = (bf16*)(ws + OFF_DT);
  bf16* WXPAD = (bf16*)(ws + OFF_WXPAD);
  bf16* P = (bf16*)(ws + OFF_P);
  bf16* Lc = (bf16*)(ws + OFF_L);

  float* out = (float*)d_out;             // (2,1024,2048) = 4194304 f32
  float* out_conv = out + 4194304;        // (2,4096,4)
  float* out_last = out + 4227072;        // (2,4096,16)
  // In (f32, 16.78 MB) parks in the `out` region: written by phase2, read by
  // phase3, then fully overwritten by GEMM3 (same-stream ordering).
  float* In = out;

  wxpad_prep<<<4096, 256, 0, stream>>>(W_x, WXPAD);
  hipMemsetAsync(XDBL, 0, 2048UL * 256 * 4, stream);

  const bool castOK = ws_size >= WS_NEED_CAST;
  if (castOK) {
    bf16* HBF = (bf16*)(ws + OFF_HBF);
    bf16* WINBF = (bf16*)(ws + OFF_WINBF);
    bf16* WDTBF = (bf16*)(ws + OFF_WDTBF);
    bf16* WOUTBF = (bf16*)(ws + OFF_WOUTBF);
    cast_all<<<14592, 256, 0, stream>>>(hidden, W_in, W_dt, W_out, HBF, WINBF,
                                        WDTBF, WOUTBF);
    gemm_bt<0, 0, 0><<<dim3(16, 64, 1), 256, 0, stream>>>(HBF, WINBF, XZ,
                                                          nullptr, 2048, 8192,
                                                          2048);
    conv_kernel<<<32768, 256, 0, stream>>>(XZ, conv_w, conv_b, XC);
    convstate_kernel<<<128, 256, 0, stream>>>(XZ, out_conv);
    gemm_bt<1, 0, 0><<<dim3(16, 2, 8), 256, 0, stream>>>(XC, WXPAD, XDBL,
                                                         nullptr, 2048, 256,
                                                         4096);
    dtcast_kernel<<<1024, 256, 0, stream>>>(XDBL, DT);
    gemm_bt<2, 0, 0><<<dim3(16, 32, 1), 256, 0, stream>>>(DT, WDTBF, DELTA,
                                                          b_dt, 2048, 4096,
                                                          128);
    scan_phase1<<<dim3(32, NCH), 256, 0, stream>>>(DELTA, XC, XDBL, A_log, P,
                                                   Lc);
    scan_phase2<<<32, 256, 0, stream>>>(P, Lc, In, out_last);
    scan_phase3<<<dim3(32, NCH), 256, 0, stream>>>(DELTA, XC, XZ, XDBL, A_log,
                                                   Dvec, In, Y);
    gemm_bt<3, 0, 0><<<dim3(16, 16, 1), 256, 0, stream>>>(Y, WOUTBF, out, b_out,
                                                          2048, 2048, 4096);
  } else {
    // fallback: f32-staged GEMMs
    gemm_bt<0, 1, 1><<<dim3(16, 64, 1), 256, 0, stream>>>(hidden, W_in, XZ,
                                                          nullptr, 2048, 8192,
                                                          2048);
    conv_kernel<<<32768, 256, 0, stream>>>(XZ, conv_w, conv_b, XC);
    convstate_kernel<<<128, 256, 0, stream>>>(XZ, out_conv);
    gemm_bt<1, 0, 0><<<dim3(16, 2, 8), 256, 0, stream>>>(XC, WXPAD, XDBL,
                                                         nullptr, 2048, 256,
                                                         4096);
    dtcast_kernel<<<1024, 256, 0, stream>>>(XDBL, DT);
    gemm_bt<2, 0, 1><<<dim3(16, 32, 1), 256, 0, stream>>>(DT, W_dt, DELTA, b_dt,
                                                          2048, 4096, 128);
    scan_phase1<<<dim3(32, NCH), 256, 0, stream>>>(DELTA, XC, XDBL, A_log, P,
                                                   Lc);
    scan_phase2<<<32, 256, 0, stream>>>(P, Lc, In, out_last);
    scan_phase3<<<dim3(32, NCH), 256, 0, stream>>>(DELTA, XC, XZ, XDBL, A_log,
                                                   Dvec, In, Y);
    gemm_bt<3, 0, 1><<<dim3(16, 16, 1), 256, 0, stream>>>(Y, W_out, out, b_out,
                                                          2048, 2048, 4096);
  }
}

// Round 7
// 536.494 us; speedup vs baseline: 2.1138x; 1.0153x over previous
//
#include <hip/hip_runtime.h>
#include <stdint.h>
#include <stddef.h>

typedef __bf16 bf16;
typedef __attribute__((ext_vector_type(8))) __bf16 bf16x8;
typedef __attribute__((ext_vector_type(4))) float floatx4;

#define GAS __attribute__((address_space(1)))
#define LAS __attribute__((address_space(3)))

__device__ __forceinline__ void async16(const void* g, void* l) {
  __builtin_amdgcn_global_load_lds((const GAS void*)g, (LAS void*)l, 16, 0, 0);
}

__device__ __forceinline__ bf16x8 cvt8(const float* p) {
  floatx4 a = *(const floatx4*)p;
  floatx4 b = *(const floatx4*)(p + 4);
  bf16x8 r;
  r[0] = (bf16)a[0]; r[1] = (bf16)a[1]; r[2] = (bf16)a[2]; r[3] = (bf16)a[3];
  r[4] = (bf16)b[0]; r[5] = (bf16)b[1]; r[6] = (bf16)b[2]; r[7] = (bf16)b[3];
  return r;
}

// ---------------------------------------------------------------------------
// Generic "bt" GEMM: C[M,N] = A[M,K_eff] @ B[N,K_eff]^T with row strides
// lda/ldb (elements). AF/BF: f32 operand (VGPR+cvt+ds_write staging) vs bf16
// (async global_load_lds). TM: 128 (4 waves 2x2 of 64x64, 16 MFMA/wave/iter)
// or 64 (4 waves 1x4 of 64x32, 8 MFMA/wave/iter — 2x blocks for occupancy on
// small/skinny GEMMs). BK=32, 256 thr, mfma_f32_16x16x32_bf16.
// EPI: 0 bf16 store | 1 f32 atomicAdd (split-K) | 2 bf16 softplus(v+bias) |
//      3 f32 (v+bias)
// ---------------------------------------------------------------------------
template <int EPI, int AF, int BF, int TM>
__global__ __launch_bounds__(256, 2) void gemm_bt(
    const void* __restrict__ Aptr, const void* __restrict__ Bptr,
    void* __restrict__ Cout, const float* __restrict__ bias,
    int M, int N, int K, int lda, int ldb) {
  __shared__ bf16 As[TM * 32];
  __shared__ bf16 Bs[128 * 32];
  const int tid = threadIdx.x;

  const int rowBase = blockIdx.x * TM;
  const int colBase = blockIdx.y * 128;
  const int kLen = K / gridDim.z;
  const int k0 = blockIdx.z * kLen;
  const int kIters = kLen / 32;

  const int sRow = tid >> 2;
  const int sCol = (tid & 3) << 3;
  const int wave = tid >> 6;
  const int lane = tid & 63;
  constexpr int MI = 4;
  constexpr int NJ = (TM == 128) ? 4 : 2;
  const int wm = (TM == 128) ? ((wave >> 1) << 6) : 0;
  const int wn = (TM == 128) ? ((wave & 1) << 6) : (wave << 5);
  const int lr = lane & 15;
  const int kg = lane >> 4;

  floatx4 acc[MI][NJ] = {};

  for (int kt = 0; kt < kIters; ++kt) {
    const int kk = k0 + kt * 32;
    __syncthreads();  // prev iter's LDS reads done before overwrite
    if constexpr (AF) {
      const float* pa =
          (const float*)Aptr + (size_t)(rowBase + sRow) * lda + kk + sCol;
      *(bf16x8*)&As[tid * 8] = cvt8(pa);
      if constexpr (TM == 128)
        *(bf16x8*)&As[2048 + tid * 8] = cvt8(pa + (size_t)64 * lda);
    } else {
      const bf16* pa =
          (const bf16*)Aptr + (size_t)(rowBase + sRow) * lda + kk + sCol;
      async16(pa, &As[tid * 8]);
      if constexpr (TM == 128)
        async16(pa + (size_t)64 * lda, &As[2048 + tid * 8]);
    }
    if constexpr (BF) {
      const float* pb =
          (const float*)Bptr + (size_t)(colBase + sRow) * ldb + kk + sCol;
      *(bf16x8*)&Bs[tid * 8] = cvt8(pb);
      *(bf16x8*)&Bs[2048 + tid * 8] = cvt8(pb + (size_t)64 * ldb);
    } else {
      const bf16* pb =
          (const bf16*)Bptr + (size_t)(colBase + sRow) * ldb + kk + sCol;
      async16(pb, &Bs[tid * 8]);
      async16(pb + (size_t)64 * ldb, &Bs[2048 + tid * 8]);
    }
    __syncthreads();  // staging complete -> tile visible

    bf16x8 af[MI], bg[NJ];
#pragma unroll
    for (int i = 0; i < MI; ++i)
      af[i] = *(const bf16x8*)&As[(wm + i * 16 + lr) * 32 + kg * 8];
#pragma unroll
    for (int j = 0; j < NJ; ++j)
      bg[j] = *(const bf16x8*)&Bs[(wn + j * 16 + lr) * 32 + kg * 8];
#pragma unroll
    for (int i = 0; i < MI; ++i)
#pragma unroll
      for (int j = 0; j < NJ; ++j)
        acc[i][j] = __builtin_amdgcn_mfma_f32_16x16x32_bf16(af[i], bg[j],
                                                            acc[i][j], 0, 0, 0);
  }

  // epilogue: C/D layout col = lane&15, row = (lane>>4)*4 + reg  [m89]
#pragma unroll
  for (int i = 0; i < MI; ++i) {
#pragma unroll
    for (int j = 0; j < NJ; ++j) {
      const int col = colBase + wn + j * 16 + lr;
      float bv = 0.f;
      if constexpr (EPI == 2 || EPI == 3) bv = bias[col];
#pragma unroll
      for (int r = 0; r < 4; ++r) {
        const int row = rowBase + wm + i * 16 + kg * 4 + r;
        const size_t idx = (size_t)row * N + col;
        float v = acc[i][j][r];
        if constexpr (EPI == 0) {
          ((bf16*)Cout)[idx] = (bf16)v;
        } else if constexpr (EPI == 1) {
          atomicAdd((float*)Cout + idx, v);
        } else if constexpr (EPI == 2) {
          v += bv;
          // softplus = ln(1+e^v); for v>20, ln(1+e^v)==v to f32 precision.
          const float t = __expf(v);
          const float sp = (v > 20.f) ? v : __logf(1.f + t);
          ((bf16*)Cout)[idx] = (bf16)sp;
        } else {
          ((float*)Cout)[idx] = v + bv;
        }
      }
    }
  }
}

// ---------------------------------------------------------------------------
// Fused prep: f32->bf16 casts (hidden|W_in|W_dt|W_out), W_x pad-cast 160->256
// rows, and XDBL zero-init. One dispatch, 8-elem chunks.
// ---------------------------------------------------------------------------
#define PC0 524288UL    // hidden chunks
#define PC1 2621440UL   // +W_in
#define PC2 2686976UL   // +W_dt
#define PC3 3735552UL   // +W_out
#define PC4 3866624UL   // +WXPAD (dest 256x4096)
#define PC5 3932160UL   // +XDBL zero (524288 f32)
__global__ __launch_bounds__(256) void prep_all(
    const float* __restrict__ h, const float* __restrict__ wi,
    const float* __restrict__ wd, const float* __restrict__ wo,
    const float* __restrict__ wx, bf16* __restrict__ hb,
    bf16* __restrict__ wib, bf16* __restrict__ wdb, bf16* __restrict__ wob,
    bf16* __restrict__ wxp, float* __restrict__ xdbl) {
  const size_t c = (size_t)blockIdx.x * 256 + threadIdx.x;
  if (c < PC0) {
    const size_t e = c * 8;
    *(bf16x8*)&hb[e] = cvt8(&h[e]);
  } else if (c < PC1) {
    const size_t e = (c - PC0) * 8;
    *(bf16x8*)&wib[e] = cvt8(&wi[e]);
  } else if (c < PC2) {
    const size_t e = (c - PC1) * 8;
    *(bf16x8*)&wdb[e] = cvt8(&wd[e]);
  } else if (c < PC3) {
    const size_t e = (c - PC2) * 8;
    *(bf16x8*)&wob[e] = cvt8(&wo[e]);
  } else if (c < PC4) {
    const size_t e = (c - PC3) * 8;
    if ((e >> 12) < 160) {
      *(bf16x8*)&wxp[e] = cvt8(&wx[e]);
    } else {
      bf16x8 z = {};
      *(bf16x8*)&wxp[e] = z;
    }
  } else {
    const size_t e = (c - PC4) * 8;
    floatx4 z = {};
    *(floatx4*)&xdbl[e] = z;
    *(floatx4*)&xdbl[e + 4] = z;
  }
}

// W_x pad (fallback path only)
__global__ void wxpad_prep(const float* __restrict__ Wx,
                           bf16* __restrict__ WXPAD) {
  const int idx = blockIdx.x * 256 + threadIdx.x;
  const int row = idx >> 12;
  WXPAD[idx] = (row < 160) ? (bf16)Wx[idx] : (bf16)0.f;
}

// Depthwise causal conv (K=4) + bias + SiLU; fused conv_state output.
__global__ void conv_kernel(const bf16* __restrict__ XZ,
                            const float* __restrict__ conv_w,
                            const float* __restrict__ conv_b,
                            bf16* __restrict__ XC,
                            float* __restrict__ outConv) {
  const int idx = blockIdx.x * 256 + threadIdx.x;  // 2048*4096
  const int d = idx & 4095;
  const int row = idx >> 12;
  const int l = row & 1023;
  float acc = conv_b[d];
#pragma unroll
  for (int k = 0; k < 4; ++k) {
    if (l - 3 + k >= 0)
      acc += conv_w[d * 4 + k] * (float)XZ[(size_t)(row - 3 + k) * 8192 + d];
  }
  const float s = acc / (1.f + __expf(-acc));
  XC[(size_t)row * 4096 + d] = (bf16)s;
  if (idx < 32768) {  // conv_state: out[b,dd,k] = x[b, 1020+k, dd]
    const int k = idx & 3;
    const int dd = (idx >> 2) & 4095;
    const int b = idx >> 14;
    outConv[idx] = (float)XZ[(size_t)(b * 1024 + 1020 + k) * 8192 + dd];
  }
}

// ---------------------------------------------------------------------------
// Chunked parallel scan (32 chunks of 32). phase1: per-chunk (P=prod dA,
// L=state from 0). phase2: sequential combine -> per-chunk incoming state In
// (f32) + final state out. phase3: replay chunk from In, fuse epilogue.
// ---------------------------------------------------------------------------
#define NCH 32
#define CLEN 32
#define LOG2E 1.44269504088896f

__global__ __launch_bounds__(256) void scan_phase1(
    const bf16* __restrict__ DELTA, const bf16* __restrict__ XC,
    const float* __restrict__ XDBL, const float* __restrict__ A_log,
    bf16* __restrict__ P, bf16* __restrict__ Lc) {
  const int bd = blockIdx.x * 256 + threadIdx.x;  // 0..8191
  const int c = blockIdx.y;
  const int b = bd >> 12;
  const int d = bd & 4095;
  float A2[16], st[16], p[16];
#pragma unroll
  for (int n = 0; n < 16; ++n) {
    A2[n] = -__expf(A_log[d * 16 + n]) * LOG2E;
    st[n] = 0.f;
    p[n] = 1.f;
  }
  size_t row = (size_t)b * 1024 + (size_t)c * CLEN;
  for (int t = 0; t < CLEN; ++t, ++row) {
    const float dlt = (float)DELTA[row * 4096 + d];
    const float u = (float)XC[row * 4096 + d];
    const float* __restrict__ Bp = XDBL + row * 256 + 128;  // wave-uniform
    const float du = dlt * u;
#pragma unroll
    for (int n = 0; n < 16; ++n) {
      const float dA = exp2f(dlt * A2[n]);
      st[n] = dA * st[n] + du * Bp[n];
      p[n] *= dA;
    }
  }
  const size_t o = ((size_t)c * 8192 + bd) * 16;
  bf16x8 pk[2], lk[2];
#pragma unroll
  for (int n = 0; n < 16; ++n) {
    pk[n >> 3][n & 7] = (bf16)p[n];
    lk[n >> 3][n & 7] = (bf16)st[n];
  }
  *(bf16x8*)&P[o] = pk[0];
  *(bf16x8*)&P[o + 8] = pk[1];
  *(bf16x8*)&Lc[o] = lk[0];
  *(bf16x8*)&Lc[o + 8] = lk[1];
}

__global__ __launch_bounds__(256) void scan_phase2(
    const bf16* __restrict__ P, const bf16* __restrict__ Lc,
    float* __restrict__ In, float* __restrict__ lastOut) {
  const int bd = blockIdx.x * 256 + threadIdx.x;  // 0..8191
  float st[16] = {};
  for (int c = 0; c < NCH; ++c) {
    const size_t o = ((size_t)c * 8192 + bd) * 16;
    const bf16x8 p0 = *(const bf16x8*)&P[o];
    const bf16x8 p1 = *(const bf16x8*)&P[o + 8];
    const bf16x8 l0 = *(const bf16x8*)&Lc[o];
    const bf16x8 l1 = *(const bf16x8*)&Lc[o + 8];
    floatx4 w[4];
#pragma unroll
    for (int n = 0; n < 16; ++n) w[n >> 2][n & 3] = st[n];
#pragma unroll
    for (int q = 0; q < 4; ++q) *(floatx4*)&In[o + q * 4] = w[q];
#pragma unroll
    for (int n = 0; n < 8; ++n) {
      st[n] = (float)p0[n] * st[n] + (float)l0[n];
      st[8 + n] = (float)p1[n] * st[8 + n] + (float)l1[n];
    }
  }
  const int b = bd >> 12;
  const int d = bd & 4095;
#pragma unroll
  for (int n = 0; n < 16; ++n)
    lastOut[(size_t)b * 65536 + d * 16 + n] = st[n];
}

__global__ __launch_bounds__(256) void scan_phase3(
    const bf16* __restrict__ DELTA, const bf16* __restrict__ XC,
    const bf16* __restrict__ XZ, const float* __restrict__ XDBL,
    const float* __restrict__ A_log, const float* __restrict__ Dp,
    const float* __restrict__ In, bf16* __restrict__ Y) {
  const int bd = blockIdx.x * 256 + threadIdx.x;
  const int c = blockIdx.y;
  const int b = bd >> 12;
  const int d = bd & 4095;
  float A2[16], st[16];
  const size_t o = ((size_t)c * 8192 + bd) * 16;
#pragma unroll
  for (int q = 0; q < 4; ++q) {
    const floatx4 v = *(const floatx4*)&In[o + q * 4];
#pragma unroll
    for (int j = 0; j < 4; ++j) st[q * 4 + j] = v[j];
  }
#pragma unroll
  for (int n = 0; n < 16; ++n)
    A2[n] = -__expf(A_log[d * 16 + n]) * LOG2E;
  const float Dd = Dp[d];
  size_t row = (size_t)b * 1024 + (size_t)c * CLEN;
  for (int t = 0; t < CLEN; ++t, ++row) {
    const float dlt = (float)DELTA[row * 4096 + d];
    const float u = (float)XC[row * 4096 + d];
    const float z = (float)XZ[row * 8192 + 4096 + d];
    const float* __restrict__ Bp = XDBL + row * 256 + 128;
    const float du = dlt * u;
    float y = 0.f;
#pragma unroll
    for (int n = 0; n < 16; ++n) {
      const float dA = exp2f(dlt * A2[n]);
      st[n] = dA * st[n] + du * Bp[n];
      y += st[n] * Bp[16 + n];
    }
    const float sig = 1.f / (1.f + __expf(-z));
    Y[row * 4096 + d] = (bf16)((y + Dd * u) * (z * sig));
  }
}

// ---------------------------------------------------------------------------
// Workspace layout (bytes)
// ---------------------------------------------------------------------------
#define OFF_XZ 0UL                 // bf16 2048x8192
#define OFF_XC 33554432UL          // bf16 2048x4096
#define OFF_DELTA 50331648UL       // bf16 2048x4096 (slot sized for f32)
#define OFF_Y 83886080UL           // bf16 2048x4096
#define OFF_XDBL 100663296UL       // f32  2048x256
#define OFF_WXPAD 103284736UL      // bf16 256x4096
#define OFF_P 105381888UL          // bf16 32x8192x16
#define OFF_L 113770496UL          // bf16 32x8192x16
#define OFF_HBF 122159104UL        // bf16 2048x2048
#define OFF_WINBF 130547712UL      // bf16 8192x2048
#define OFF_WDTBF 164102144UL      // bf16 4096x128
#define OFF_WOUTBF 165150720UL     // bf16 2048x4096
#define WS_NEED_CAST 181927936UL   // ~173.5 MB

extern "C" void kernel_launch(void* const* d_in, const int* in_sizes, int n_in,
                              void* d_out, int out_size, void* d_ws,
                              size_t ws_size, hipStream_t stream) {
  const float* hidden = (const float*)d_in[0];
  const float* W_in = (const float*)d_in[1];
  const float* conv_w = (const float*)d_in[2];
  const float* conv_b = (const float*)d_in[3];
  const float* W_x = (const float*)d_in[4];
  const float* W_dt = (const float*)d_in[5];
  const float* b_dt = (const float*)d_in[6];
  const float* A_log = (const float*)d_in[7];
  const float* Dvec = (const float*)d_in[8];
  const float* W_out = (const float*)d_in[9];
  const float* b_out = (const float*)d_in[10];

  char* ws = (char*)d_ws;
  bf16* XZ = (bf16*)(ws + OFF_XZ);
  bf16* XC = (bf16*)(ws + OFF_XC);
  bf16* DELTA = (bf16*)(ws + OFF_DELTA);
  bf16* Y = (bf16*)(ws + OFF_Y);
  float* XDBL = (float*)(ws + OFF_XDBL);
  bf16* WXPAD = (bf16*)(ws + OFF_WXPAD);
  bf16* P = (bf16*)(ws + OFF_P);
  bf16* Lc = (bf16*)(ws + OFF_L);

  float* out = (float*)d_out;             // (2,1024,2048) = 4194304 f32
  float* out_conv = out + 4194304;        // (2,4096,4)
  float* out_last = out + 4227072;        // (2,4096,16)
  // In (f32, 16.78 MB) parks in the `out` region: written by phase2, read by
  // phase3, then fully overwritten by GEMM3 (same-stream ordering).
  float* In = out;

  const bool castOK = ws_size >= WS_NEED_CAST;
  if (castOK) {
    bf16* HBF = (bf16*)(ws + OFF_HBF);
    bf16* WINBF = (bf16*)(ws + OFF_WINBF);
    bf16* WDTBF = (bf16*)(ws + OFF_WDTBF);
    bf16* WOUTBF = (bf16*)(ws + OFF_WOUTBF);
    prep_all<<<15360, 256, 0, stream>>>(hidden, W_in, W_dt, W_out, W_x, HBF,
                                        WINBF, WDTBF, WOUTBF, WXPAD, XDBL);
    // GEMM1: XZ = HBF @ WINBF^T
    gemm_bt<0, 0, 0, 128><<<dim3(16, 64, 1), 256, 0, stream>>>(
        HBF, WINBF, XZ, nullptr, 2048, 8192, 2048, 2048, 2048);
    conv_kernel<<<32768, 256, 0, stream>>>(XZ, conv_w, conv_b, XC, out_conv);
    // GEMM2 (split-K=16, f32 atomics): XDBL = XC @ WXPAD^T
    gemm_bt<1, 0, 0, 128><<<dim3(16, 2, 16), 256, 0, stream>>>(
        XC, WXPAD, XDBL, nullptr, 2048, 256, 4096, 4096, 4096);
    // GEMM_dt (TM=64, A = XDBL dt-cols f32 lda=256): DELTA = softplus(.)
    gemm_bt<2, 1, 0, 64><<<dim3(32, 32, 1), 256, 0, stream>>>(
        XDBL, WDTBF, DELTA, b_dt, 2048, 4096, 128, 256, 128);
    scan_phase1<<<dim3(32, NCH), 256, 0, stream>>>(DELTA, XC, XDBL, A_log, P,
                                                   Lc);
    scan_phase2<<<32, 256, 0, stream>>>(P, Lc, In, out_last);
    scan_phase3<<<dim3(32, NCH), 256, 0, stream>>>(DELTA, XC, XZ, XDBL, A_log,
                                                   Dvec, In, Y);
    // GEMM3 (TM=64, 512 blocks): out = Y @ WOUTBF^T + b_out
    gemm_bt<3, 0, 0, 64><<<dim3(32, 16, 1), 256, 0, stream>>>(
        Y, WOUTBF, out, b_out, 2048, 2048, 4096, 4096, 4096);
  } else {
    // fallback: f32-staged GEMMs, no cast buffers
    wxpad_prep<<<4096, 256, 0, stream>>>(W_x, WXPAD);
    hipMemsetAsync(XDBL, 0, 2048UL * 256 * 4, stream);
    gemm_bt<0, 1, 1, 128><<<dim3(16, 64, 1), 256, 0, stream>>>(
        hidden, W_in, XZ, nullptr, 2048, 8192, 2048, 2048, 2048);
    conv_kernel<<<32768, 256, 0, stream>>>(XZ, conv_w, conv_b, XC, out_conv);
    gemm_bt<1, 0, 0, 128><<<dim3(16, 2, 16), 256, 0, stream>>>(
        XC, WXPAD, XDBL, nullptr, 2048, 256, 4096, 4096, 4096);
    gemm_bt<2, 1, 1, 64><<<dim3(32, 32, 1), 256, 0, stream>>>(
        XDBL, W_dt, DELTA, b_dt, 2048, 4096, 128, 256, 128);
    scan_phase1<<<dim3(32, NCH), 256, 0, stream>>>(DELTA, XC, XDBL, A_log, P,
                                                   Lc);
    scan_phase2<<<32, 256, 0, stream>>>(P, Lc, In, out_last);
    scan_phase3<<<dim3(32, NCH), 256, 0, stream>>>(DELTA, XC, XZ, XDBL, A_log,
                                                   Dvec, In, Y);
    gemm_bt<3, 0, 1, 64><<<dim3(32, 16, 1), 256, 0, stream>>>(
        Y, W_out, out, b_out, 2048, 2048, 4096, 4096, 4096);
  }
}

// Round 8
// 529.894 us; speedup vs baseline: 2.1401x; 1.0125x over previous
//
#include <hip/hip_runtime.h>
#include <stdint.h>
#include <stddef.h>

typedef __bf16 bf16;
typedef __attribute__((ext_vector_type(8))) __bf16 bf16x8;
typedef __attribute__((ext_vector_type(4))) float floatx4;

#define GAS __attribute__((address_space(1)))
#define LAS __attribute__((address_space(3)))

__device__ __forceinline__ void async16(const void* g, void* l) {
  __builtin_amdgcn_global_load_lds((const GAS void*)g, (LAS void*)l, 16, 0, 0);
}

__device__ __forceinline__ bf16x8 cvt8(const float* p) {
  floatx4 a = *(const floatx4*)p;
  floatx4 b = *(const floatx4*)(p + 4);
  bf16x8 r;
  r[0] = (bf16)a[0]; r[1] = (bf16)a[1]; r[2] = (bf16)a[2]; r[3] = (bf16)a[3];
  r[4] = (bf16)b[0]; r[5] = (bf16)b[1]; r[6] = (bf16)b[2]; r[7] = (bf16)b[3];
  return r;
}

// ---------------------------------------------------------------------------
// Generic "bt" GEMM: C[M,N] = A[M,K_eff] @ B[N,K_eff]^T with row strides
// lda/ldb (elements). AF/BF: f32 operand (VGPR+cvt+ds_write staging) vs bf16
// (async global_load_lds). TM: 128 (4 waves 2x2 of 64x64) or 64 (4 waves 1x4
// of 64x32). BK=32, 256 thr, mfma_f32_16x16x32_bf16.
// EPI: 0 bf16 store | 1 f32 atomicAdd | 2 bf16 softplus(v+bias) |
//      3 f32 (v+bias) | 4 f32 store to per-z partial slab (split-K, no atomics)
// ---------------------------------------------------------------------------
template <int EPI, int AF, int BF, int TM>
__global__ __launch_bounds__(256, 4) void gemm_bt(
    const void* __restrict__ Aptr, const void* __restrict__ Bptr,
    void* __restrict__ Cout, const float* __restrict__ bias,
    int M, int N, int K, int lda, int ldb) {
  __shared__ bf16 As[TM * 32];
  __shared__ bf16 Bs[128 * 32];
  const int tid = threadIdx.x;

  const int rowBase = blockIdx.x * TM;
  const int colBase = blockIdx.y * 128;
  const int kLen = K / gridDim.z;
  const int k0 = blockIdx.z * kLen;
  const int kIters = kLen / 32;

  const int sRow = tid >> 2;
  const int sCol = (tid & 3) << 3;
  const int wave = tid >> 6;
  const int lane = tid & 63;
  constexpr int MI = 4;
  constexpr int NJ = (TM == 128) ? 4 : 2;
  const int wm = (TM == 128) ? ((wave >> 1) << 6) : 0;
  const int wn = (TM == 128) ? ((wave & 1) << 6) : (wave << 5);
  const int lr = lane & 15;
  const int kg = lane >> 4;

  floatx4 acc[MI][NJ] = {};

  for (int kt = 0; kt < kIters; ++kt) {
    const int kk = k0 + kt * 32;
    __syncthreads();  // prev iter's LDS reads done before overwrite
    if constexpr (AF) {
      const float* pa =
          (const float*)Aptr + (size_t)(rowBase + sRow) * lda + kk + sCol;
      *(bf16x8*)&As[tid * 8] = cvt8(pa);
      if constexpr (TM == 128)
        *(bf16x8*)&As[2048 + tid * 8] = cvt8(pa + (size_t)64 * lda);
    } else {
      const bf16* pa =
          (const bf16*)Aptr + (size_t)(rowBase + sRow) * lda + kk + sCol;
      async16(pa, &As[tid * 8]);
      if constexpr (TM == 128)
        async16(pa + (size_t)64 * lda, &As[2048 + tid * 8]);
    }
    if constexpr (BF) {
      const float* pb =
          (const float*)Bptr + (size_t)(colBase + sRow) * ldb + kk + sCol;
      *(bf16x8*)&Bs[tid * 8] = cvt8(pb);
      *(bf16x8*)&Bs[2048 + tid * 8] = cvt8(pb + (size_t)64 * ldb);
    } else {
      const bf16* pb =
          (const bf16*)Bptr + (size_t)(colBase + sRow) * ldb + kk + sCol;
      async16(pb, &Bs[tid * 8]);
      async16(pb + (size_t)64 * ldb, &Bs[2048 + tid * 8]);
    }
    __syncthreads();  // staging complete -> tile visible

    bf16x8 af[MI], bg[NJ];
#pragma unroll
    for (int i = 0; i < MI; ++i)
      af[i] = *(const bf16x8*)&As[(wm + i * 16 + lr) * 32 + kg * 8];
#pragma unroll
    for (int j = 0; j < NJ; ++j)
      bg[j] = *(const bf16x8*)&Bs[(wn + j * 16 + lr) * 32 + kg * 8];
#pragma unroll
    for (int i = 0; i < MI; ++i)
#pragma unroll
      for (int j = 0; j < NJ; ++j)
        acc[i][j] = __builtin_amdgcn_mfma_f32_16x16x32_bf16(af[i], bg[j],
                                                            acc[i][j], 0, 0, 0);
  }

  // epilogue: C/D layout col = lane&15, row = (lane>>4)*4 + reg  [m89]
#pragma unroll
  for (int i = 0; i < MI; ++i) {
#pragma unroll
    for (int j = 0; j < NJ; ++j) {
      const int col = colBase + wn + j * 16 + lr;
      float bv = 0.f;
      if constexpr (EPI == 2 || EPI == 3) bv = bias[col];
#pragma unroll
      for (int r = 0; r < 4; ++r) {
        const int row = rowBase + wm + i * 16 + kg * 4 + r;
        const size_t idx = (size_t)row * N + col;
        float v = acc[i][j][r];
        if constexpr (EPI == 0) {
          ((bf16*)Cout)[idx] = (bf16)v;
        } else if constexpr (EPI == 1) {
          atomicAdd((float*)Cout + idx, v);
        } else if constexpr (EPI == 2) {
          v += bv;
          // softplus = ln(1+e^v); for v>20, ln(1+e^v)==v to f32 precision.
          const float t = __expf(v);
          const float sp = (v > 20.f) ? v : __logf(1.f + t);
          ((bf16*)Cout)[idx] = (bf16)sp;
        } else if constexpr (EPI == 3) {
          ((float*)Cout)[idx] = v + bv;
        } else {
          // split-K partial: distinct slab per z, no contention
          ((float*)Cout)[(size_t)blockIdx.z * 524288 + idx] = v;
        }
      }
    }
  }
}

// sum 8 split-K partial slabs -> XDBL (2048x256 f32)
__global__ __launch_bounds__(256) void reduce_xdbl(
    const float* __restrict__ part, float* __restrict__ xdbl) {
  const size_t i4 = ((size_t)blockIdx.x * 256 + threadIdx.x) * 4;  // 524288/4
  floatx4 s = {};
#pragma unroll
  for (int z = 0; z < 8; ++z) {
    const floatx4 v = *(const floatx4*)&part[(size_t)z * 524288 + i4];
    s[0] += v[0]; s[1] += v[1]; s[2] += v[2]; s[3] += v[3];
  }
  *(floatx4*)&xdbl[i4] = s;
}

// ---------------------------------------------------------------------------
// Fused prep: f32->bf16 casts (hidden|W_in|W_dt|W_out) + W_x pad-cast.
// ---------------------------------------------------------------------------
#define PC0 524288UL    // hidden chunks
#define PC1 2621440UL   // +W_in
#define PC2 2686976UL   // +W_dt
#define PC3 3735552UL   // +W_out
#define PC4 3866624UL   // +WXPAD (dest 256x4096)
__global__ __launch_bounds__(256) void prep_all(
    const float* __restrict__ h, const float* __restrict__ wi,
    const float* __restrict__ wd, const float* __restrict__ wo,
    const float* __restrict__ wx, bf16* __restrict__ hb,
    bf16* __restrict__ wib, bf16* __restrict__ wdb, bf16* __restrict__ wob,
    bf16* __restrict__ wxp) {
  const size_t c = (size_t)blockIdx.x * 256 + threadIdx.x;
  if (c < PC0) {
    const size_t e = c * 8;
    *(bf16x8*)&hb[e] = cvt8(&h[e]);
  } else if (c < PC1) {
    const size_t e = (c - PC0) * 8;
    *(bf16x8*)&wib[e] = cvt8(&wi[e]);
  } else if (c < PC2) {
    const size_t e = (c - PC1) * 8;
    *(bf16x8*)&wdb[e] = cvt8(&wd[e]);
  } else if (c < PC3) {
    const size_t e = (c - PC2) * 8;
    *(bf16x8*)&wob[e] = cvt8(&wo[e]);
  } else if (c < PC4) {
    const size_t e = (c - PC3) * 8;
    if ((e >> 12) < 160) {
      *(bf16x8*)&wxp[e] = cvt8(&wx[e]);
    } else {
      bf16x8 z = {};
      *(bf16x8*)&wxp[e] = z;
    }
  }
}

// W_x pad (fallback path only)
__global__ void wxpad_prep(const float* __restrict__ Wx,
                           bf16* __restrict__ WXPAD) {
  const int idx = blockIdx.x * 256 + threadIdx.x;
  const int row = idx >> 12;
  WXPAD[idx] = (row < 160) ? (bf16)Wx[idx] : (bf16)0.f;
}

// Depthwise causal conv (K=4) + bias + SiLU; fused conv_state output.
__global__ void conv_kernel(const bf16* __restrict__ XZ,
                            const float* __restrict__ conv_w,
                            const float* __restrict__ conv_b,
                            bf16* __restrict__ XC,
                            float* __restrict__ outConv) {
  const int idx = blockIdx.x * 256 + threadIdx.x;  // 2048*4096
  const int d = idx & 4095;
  const int row = idx >> 12;
  const int l = row & 1023;
  float acc = conv_b[d];
#pragma unroll
  for (int k = 0; k < 4; ++k) {
    if (l - 3 + k >= 0)
      acc += conv_w[d * 4 + k] * (float)XZ[(size_t)(row - 3 + k) * 8192 + d];
  }
  const float s = acc / (1.f + __expf(-acc));
  XC[(size_t)row * 4096 + d] = (bf16)s;
  if (idx < 32768) {  // conv_state: out[b,dd,k] = x[b, 1020+k, dd]
    const int k = idx & 3;
    const int dd = (idx >> 2) & 4095;
    const int b = idx >> 14;
    outConv[idx] = (float)XZ[(size_t)(b * 1024 + 1020 + k) * 8192 + dd];
  }
}

// ---------------------------------------------------------------------------
// Chunked parallel scan (32 chunks of 32).
// ---------------------------------------------------------------------------
#define NCH 32
#define CLEN 32
#define LOG2E 1.44269504088896f

__global__ __launch_bounds__(256) void scan_phase1(
    const bf16* __restrict__ DELTA, const bf16* __restrict__ XC,
    const float* __restrict__ XDBL, const float* __restrict__ A_log,
    bf16* __restrict__ P, bf16* __restrict__ Lc) {
  const int bd = blockIdx.x * 256 + threadIdx.x;  // 0..8191
  const int c = blockIdx.y;
  const int b = bd >> 12;
  const int d = bd & 4095;
  float A2[16], st[16], p[16];
#pragma unroll
  for (int n = 0; n < 16; ++n) {
    A2[n] = -__expf(A_log[d * 16 + n]) * LOG2E;
    st[n] = 0.f;
    p[n] = 1.f;
  }
  size_t row = (size_t)b * 1024 + (size_t)c * CLEN;
  for (int t = 0; t < CLEN; ++t, ++row) {
    const float dlt = (float)DELTA[row * 4096 + d];
    const float u = (float)XC[row * 4096 + d];
    const float* __restrict__ Bp = XDBL + row * 256 + 128;  // wave-uniform
    const float du = dlt * u;
#pragma unroll
    for (int n = 0; n < 16; ++n) {
      const float dA = exp2f(dlt * A2[n]);
      st[n] = dA * st[n] + du * Bp[n];
      p[n] *= dA;
    }
  }
  const size_t o = ((size_t)c * 8192 + bd) * 16;
  bf16x8 pk[2], lk[2];
#pragma unroll
  for (int n = 0; n < 16; ++n) {
    pk[n >> 3][n & 7] = (bf16)p[n];
    lk[n >> 3][n & 7] = (bf16)st[n];
  }
  *(bf16x8*)&P[o] = pk[0];
  *(bf16x8*)&P[o + 8] = pk[1];
  *(bf16x8*)&Lc[o] = lk[0];
  *(bf16x8*)&Lc[o + 8] = lk[1];
}

__global__ __launch_bounds__(256) void scan_phase2(
    const bf16* __restrict__ P, const bf16* __restrict__ Lc,
    float* __restrict__ In, float* __restrict__ lastOut) {
  const int bd = blockIdx.x * 256 + threadIdx.x;  // 0..8191
  float st[16] = {};
  for (int c = 0; c < NCH; ++c) {
    const size_t o = ((size_t)c * 8192 + bd) * 16;
    const bf16x8 p0 = *(const bf16x8*)&P[o];
    const bf16x8 p1 = *(const bf16x8*)&P[o + 8];
    const bf16x8 l0 = *(const bf16x8*)&Lc[o];
    const bf16x8 l1 = *(const bf16x8*)&Lc[o + 8];
    floatx4 w[4];
#pragma unroll
    for (int n = 0; n < 16; ++n) w[n >> 2][n & 3] = st[n];
#pragma unroll
    for (int q = 0; q < 4; ++q) *(floatx4*)&In[o + q * 4] = w[q];
#pragma unroll
    for (int n = 0; n < 8; ++n) {
      st[n] = (float)p0[n] * st[n] + (float)l0[n];
      st[8 + n] = (float)p1[n] * st[8 + n] + (float)l1[n];
    }
  }
  const int b = bd >> 12;
  const int d = bd & 4095;
#pragma unroll
  for (int n = 0; n < 16; ++n)
    lastOut[(size_t)b * 65536 + d * 16 + n] = st[n];
}

__global__ __launch_bounds__(256) void scan_phase3(
    const bf16* __restrict__ DELTA, const bf16* __restrict__ XC,
    const bf16* __restrict__ XZ, const float* __restrict__ XDBL,
    const float* __restrict__ A_log, const float* __restrict__ Dp,
    const float* __restrict__ In, bf16* __restrict__ Y) {
  const int bd = blockIdx.x * 256 + threadIdx.x;
  const int c = blockIdx.y;
  const int b = bd >> 12;
  const int d = bd & 4095;
  float A2[16], st[16];
  const size_t o = ((size_t)c * 8192 + bd) * 16;
#pragma unroll
  for (int q = 0; q < 4; ++q) {
    const floatx4 v = *(const floatx4*)&In[o + q * 4];
#pragma unroll
    for (int j = 0; j < 4; ++j) st[q * 4 + j] = v[j];
  }
#pragma unroll
  for (int n = 0; n < 16; ++n)
    A2[n] = -__expf(A_log[d * 16 + n]) * LOG2E;
  const float Dd = Dp[d];
  size_t row = (size_t)b * 1024 + (size_t)c * CLEN;
  for (int t = 0; t < CLEN; ++t, ++row) {
    const float dlt = (float)DELTA[row * 4096 + d];
    const float u = (float)XC[row * 4096 + d];
    const float z = (float)XZ[row * 8192 + 4096 + d];
    const float* __restrict__ Bp = XDBL + row * 256 + 128;
    const float du = dlt * u;
    float y = 0.f;
#pragma unroll
    for (int n = 0; n < 16; ++n) {
      const float dA = exp2f(dlt * A2[n]);
      st[n] = dA * st[n] + du * Bp[n];
      y += st[n] * Bp[16 + n];
    }
    const float sig = 1.f / (1.f + __expf(-z));
    Y[row * 4096 + d] = (bf16)((y + Dd * u) * (z * sig));
  }
}

// ---------------------------------------------------------------------------
// Workspace layout (bytes). DELTA slot holds bf16 DELTA (lower 16.8 MB) and
// the GEMM2 split-K partials (upper 16.8 MB; 8 slabs x 2 MB) — partials are
// consumed by reduce_xdbl before DELTA is written.
// ---------------------------------------------------------------------------
#define OFF_XZ 0UL                 // bf16 2048x8192
#define OFF_XC 33554432UL          // bf16 2048x4096
#define OFF_DELTA 50331648UL       // bf16 2048x4096 | +16777216: PART f32 8x524288
#define OFF_Y 83886080UL           // bf16 2048x4096
#define OFF_XDBL 100663296UL       // f32  2048x256
#define OFF_WXPAD 103284736UL      // bf16 256x4096
#define OFF_P 105381888UL          // bf16 32x8192x16
#define OFF_L 113770496UL          // bf16 32x8192x16
#define OFF_HBF 122159104UL        // bf16 2048x2048
#define OFF_WINBF 130547712UL      // bf16 8192x2048
#define OFF_WDTBF 164102144UL      // bf16 4096x128
#define OFF_WOUTBF 165150720UL     // bf16 2048x4096
#define WS_NEED_CAST 181927936UL   // ~173.5 MB

extern "C" void kernel_launch(void* const* d_in, const int* in_sizes, int n_in,
                              void* d_out, int out_size, void* d_ws,
                              size_t ws_size, hipStream_t stream) {
  const float* hidden = (const float*)d_in[0];
  const float* W_in = (const float*)d_in[1];
  const float* conv_w = (const float*)d_in[2];
  const float* conv_b = (const float*)d_in[3];
  const float* W_x = (const float*)d_in[4];
  const float* W_dt = (const float*)d_in[5];
  const float* b_dt = (const float*)d_in[6];
  const float* A_log = (const float*)d_in[7];
  const float* Dvec = (const float*)d_in[8];
  const float* W_out = (const float*)d_in[9];
  const float* b_out = (const float*)d_in[10];

  char* ws = (char*)d_ws;
  bf16* XZ = (bf16*)(ws + OFF_XZ);
  bf16* XC = (bf16*)(ws + OFF_XC);
  bf16* DELTA = (bf16*)(ws + OFF_DELTA);
  float* PART = (float*)(ws + OFF_DELTA + 16777216UL);
  bf16* Y = (bf16*)(ws + OFF_Y);
  float* XDBL = (float*)(ws + OFF_XDBL);
  bf16* WXPAD = (bf16*)(ws + OFF_WXPAD);
  bf16* P = (bf16*)(ws + OFF_P);
  bf16* Lc = (bf16*)(ws + OFF_L);

  float* out = (float*)d_out;             // (2,1024,2048) = 4194304 f32
  float* out_conv = out + 4194304;        // (2,4096,4)
  float* out_last = out + 4227072;        // (2,4096,16)
  // In (f32, 16.78 MB) parks in the `out` region: written by phase2, read by
  // phase3, then fully overwritten by GEMM3 (same-stream ordering).
  float* In = out;

  const bool castOK = ws_size >= WS_NEED_CAST;
  if (castOK) {
    bf16* HBF = (bf16*)(ws + OFF_HBF);
    bf16* WINBF = (bf16*)(ws + OFF_WINBF);
    bf16* WDTBF = (bf16*)(ws + OFF_WDTBF);
    bf16* WOUTBF = (bf16*)(ws + OFF_WOUTBF);
    prep_all<<<15104, 256, 0, stream>>>(hidden, W_in, W_dt, W_out, W_x, HBF,
                                        WINBF, WDTBF, WOUTBF, WXPAD);
    // GEMM1: XZ = HBF @ WINBF^T
    gemm_bt<0, 0, 0, 128><<<dim3(16, 64, 1), 256, 0, stream>>>(
        HBF, WINBF, XZ, nullptr, 2048, 8192, 2048, 2048, 2048);
    conv_kernel<<<32768, 256, 0, stream>>>(XZ, conv_w, conv_b, XC, out_conv);
    // GEMM2 (split-K=8 -> partial slabs, no atomics): PART[z] = XC @ WXPAD^T
    gemm_bt<4, 0, 0, 64><<<dim3(32, 2, 8), 256, 0, stream>>>(
        XC, WXPAD, PART, nullptr, 2048, 256, 4096, 4096, 4096);
    reduce_xdbl<<<512, 256, 0, stream>>>(PART, XDBL);
    // GEMM_dt (TM=64, A = XDBL dt-cols f32 lda=256): DELTA = softplus(.)
    gemm_bt<2, 1, 0, 64><<<dim3(32, 32, 1), 256, 0, stream>>>(
        XDBL, WDTBF, DELTA, b_dt, 2048, 4096, 128, 256, 128);
    scan_phase1<<<dim3(32, NCH), 256, 0, stream>>>(DELTA, XC, XDBL, A_log, P,
                                                   Lc);
    scan_phase2<<<32, 256, 0, stream>>>(P, Lc, In, out_last);
    scan_phase3<<<dim3(32, NCH), 256, 0, stream>>>(DELTA, XC, XZ, XDBL, A_log,
                                                   Dvec, In, Y);
    // GEMM3 (TM=128: B re-read 16x not 32x): out = Y @ WOUTBF^T + b_out
    gemm_bt<3, 0, 0, 128><<<dim3(16, 16, 1), 256, 0, stream>>>(
        Y, WOUTBF, out, b_out, 2048, 2048, 4096, 4096, 4096);
  } else {
    // fallback: f32-staged GEMMs, no cast buffers
    wxpad_prep<<<4096, 256, 0, stream>>>(W_x, WXPAD);
    gemm_bt<0, 1, 1, 128><<<dim3(16, 64, 1), 256, 0, stream>>>(
        hidden, W_in, XZ, nullptr, 2048, 8192, 2048, 2048, 2048);
    conv_kernel<<<32768, 256, 0, stream>>>(XZ, conv_w, conv_b, XC, out_conv);
    gemm_bt<4, 0, 0, 64><<<dim3(32, 2, 8), 256, 0, stream>>>(
        XC, WXPAD, PART, nullptr, 2048, 256, 4096, 4096, 4096);
    reduce_xdbl<<<512, 256, 0, stream>>>(PART, XDBL);
    gemm_bt<2, 1, 1, 64><<<dim3(32, 32, 1), 256, 0, stream>>>(
        XDBL, W_dt, DELTA, b_dt, 2048, 4096, 128, 256, 128);
    scan_phase1<<<dim3(32, NCH), 256, 0, stream>>>(DELTA, XC, XDBL, A_log, P,
                                                   Lc);
    scan_phase2<<<32, 256, 0, stream>>>(P, Lc, In, out_last);
    scan_phase3<<<dim3(32, NCH), 256, 0, stream>>>(DELTA, XC, XZ, XDBL, A_log,
                                                   Dvec, In, Y);
    gemm_bt<3, 0, 1, 128><<<dim3(16, 16, 1), 256, 0, stream>>>(
        Y, W_out, out, b_out, 2048, 2048, 4096, 4096, 4096);
  }
}